// Round 1
// baseline (4436.978 us; speedup 1.0000x reference)
//
#include <hip/hip_runtime.h>
#include <math.h>

// ---------------------------------------------------------------------------
// GraphEncoder: 2-layer GraphSAGE (mean agg) + temporal edge conv + masked
// segment_max.  N=100000 nodes, E=1.6M edges, dims 64->128->256->32.
//
// Key structure decisions (round 1):
//  * edge aggregation via f32 atomicAdd scatter (likely the bottleneck;
//    profile will confirm -> CSR in a later round)
//  * layer2 GEMM folded:  hs = [h1|mean2] @ (W2cat@Wts) + b2@Wts  (h2 never
//    materialized; 5x fewer FLOPs, 102MB less traffic)
//  * segment_max computed only for edges whose dst is in mask_idx (~1% of E),
//    via order-preserving u32 encoding + atomicMax; enc 0 decodes to NaN -> 0
// ---------------------------------------------------------------------------

__device__ __forceinline__ float gelu_f(float x) {
    const float c0 = 0.7978845608028654f; // sqrt(2/pi)
    float x3 = x * x * x;
    float t = tanhf(c0 * (x + 0.044715f * x3));
    return 0.5f * x * (1.0f + t);
}

// order-preserving float->u32 (monotone): max on u32 == max on float
__device__ __forceinline__ unsigned enc_f32(float f) {
    unsigned u = __float_as_uint(f);
    return (u & 0x80000000u) ? ~u : (u | 0x80000000u);
}
__device__ __forceinline__ float dec_f32(unsigned u) {
    return (u & 0x80000000u) ? __uint_as_float(u & 0x7fffffffu)
                             : __uint_as_float(~u);
}

// ---------------------------------------------------------------------------
__global__ void kzero(float4* __restrict__ p, long n4) {
    long i = (long)blockIdx.x * blockDim.x + threadIdx.x;
    long stride = (long)gridDim.x * blockDim.x;
    float4 z = make_float4(0.f, 0.f, 0.f, 0.f);
    for (; i < n4; i += stride) p[i] = z;
}

__global__ void kflag(const int* __restrict__ mask, int M, int* __restrict__ flag) {
    int i = blockIdx.x * blockDim.x + threadIdx.x;
    if (i < M) flag[mask[i]] = 1;
}

// Wc[k*64 + c2]  (c2 = mat*32 + j ; mat 0 = Wts-path (hs), 1 = Wtd-path (hd))
// Wc[k][c2] = sum_j2 W2cat[k][j2] * Wt[j2][j] ;  bc[c2] = sum_j2 b2[j2]*Wt[j2][j]
__global__ void kwc(const float* __restrict__ W2r, const float* __restrict__ W2n,
                    const float* __restrict__ b2,
                    const float* __restrict__ Wts, const float* __restrict__ Wtd,
                    float* __restrict__ Wc, float* __restrict__ bc) {
    if (blockIdx.x < 64) {
        int idx = blockIdx.x * 256 + threadIdx.x;   // 0..16383
        int k = idx >> 6, c2 = idx & 63;
        int mat = c2 >> 5, j = c2 & 31;
        const float* Wt = mat ? Wtd : Wts;
        const float* W2row = (k < 128) ? (W2r + (long)k * 256)
                                       : (W2n + (long)(k - 128) * 256);
        float acc = 0.f;
        for (int j2 = 0; j2 < 256; ++j2) acc += W2row[j2] * Wt[j2 * 32 + j];
        Wc[idx] = acc;
    } else {
        int t = threadIdx.x;
        if (t < 64) {
            int mat = t >> 5, j = t & 31;
            const float* Wt = mat ? Wtd : Wts;
            float acc = 0.f;
            for (int j2 = 0; j2 < 256; ++j2) acc += b2[j2] * Wt[j2 * 32 + j];
            bc[t] = acc;
        }
    }
}

// ---------------------------------------------------------------------------
// scatter 1: agg1[dst] += x[src] (64-dim), deg[dst] += 1.   16 threads/edge.
__global__ void kscatter1(const int* __restrict__ ei, const float* __restrict__ x,
                          float* __restrict__ agg1, float* __restrict__ deg, int E) {
    long idx = (long)blockIdx.x * blockDim.x + threadIdx.x;
    if (idx >= (long)E * 16) return;
    int e = (int)(idx >> 4), c = (int)(idx & 15);
    int s = ei[e], d = ei[E + e];
    float4 v = *(const float4*)(x + (long)s * 64 + c * 4);
    float* a = agg1 + (long)d * 64 + c * 4;
    atomicAdd(a + 0, v.x); atomicAdd(a + 1, v.y);
    atomicAdd(a + 2, v.z); atomicAdd(a + 3, v.w);
    if (c == 0) atomicAdd(deg + d, 1.0f);
}

// scatter 2: agg2[dst] += h1[src] (128-dim).   32 threads/edge.
__global__ void kscatter2(const int* __restrict__ ei, const float* __restrict__ h1,
                          float* __restrict__ agg2, int E) {
    long idx = (long)blockIdx.x * blockDim.x + threadIdx.x;
    if (idx >= (long)E * 32) return;
    int e = (int)(idx >> 5), c = (int)(idx & 31);
    int s = ei[e], d = ei[E + e];
    float4 v = *(const float4*)(h1 + (long)s * 128 + c * 4);
    float* a = agg2 + (long)d * 128 + c * 4;
    atomicAdd(a + 0, v.x); atomicAdd(a + 1, v.y);
    atomicAdd(a + 2, v.z); atomicAdd(a + 3, v.w);
}

// ---------------------------------------------------------------------------
// layer1: h1 = gelu([x | agg1/deg] @ [W1r;W1n] + b1)   in=128, out=128
// block 256, 32 nodes/block, 4x4 register tile, W (64KB) + in (16KB) in LDS.
#define NPB1 32
__global__ __launch_bounds__(256) void klayer1(
    const float* __restrict__ x, const float* __restrict__ agg1,
    const float* __restrict__ deg, const float* __restrict__ W1r,
    const float* __restrict__ W1n, const float* __restrict__ b1,
    float* __restrict__ h1, int N) {
    __shared__ float Wl[128 * 128];      // [k][col]
    __shared__ float inl[NPB1 * 128];    // [n][k]
    int t = threadIdx.x;
    for (int idx = t; idx < 128 * 128; idx += 256) {
        int k = idx >> 7, c = idx & 127;
        Wl[idx] = (k < 64) ? W1r[k * 128 + c] : W1n[(k - 64) * 128 + c];
    }
    int base = blockIdx.x * NPB1;
    for (int idx = t; idx < NPB1 * 128; idx += 256) {
        int n = idx >> 7, k = idx & 127;
        int node = base + n;
        float v = 0.f;
        if (node < N) {
            if (k < 64) v = x[(long)node * 64 + k];
            else        v = agg1[(long)node * 64 + (k - 64)] / fmaxf(deg[node], 1.0f);
        }
        inl[idx] = v;
    }
    __syncthreads();

    int cg = t & 31, ng = t >> 5;        // 32 col-groups x 8 node-groups(4 nodes)
    float4 bv = *(const float4*)(b1 + cg * 4);
    float acc[4][4];
#pragma unroll
    for (int i = 0; i < 4; ++i) { acc[i][0]=bv.x; acc[i][1]=bv.y; acc[i][2]=bv.z; acc[i][3]=bv.w; }

#pragma unroll 2
    for (int k4 = 0; k4 < 32; ++k4) {
        float4 w0 = *(const float4*)&Wl[(k4*4+0)*128 + cg*4];
        float4 w1 = *(const float4*)&Wl[(k4*4+1)*128 + cg*4];
        float4 w2 = *(const float4*)&Wl[(k4*4+2)*128 + cg*4];
        float4 w3 = *(const float4*)&Wl[(k4*4+3)*128 + cg*4];
#pragma unroll
        for (int i = 0; i < 4; ++i) {
            float4 iv = *(const float4*)&inl[(ng*4+i)*128 + k4*4];
            acc[i][0] += iv.x*w0.x + iv.y*w1.x + iv.z*w2.x + iv.w*w3.x;
            acc[i][1] += iv.x*w0.y + iv.y*w1.y + iv.z*w2.y + iv.w*w3.y;
            acc[i][2] += iv.x*w0.z + iv.y*w1.z + iv.z*w2.z + iv.w*w3.z;
            acc[i][3] += iv.x*w0.w + iv.y*w1.w + iv.z*w2.w + iv.w*w3.w;
        }
    }
#pragma unroll
    for (int i = 0; i < 4; ++i) {
        int node = base + ng * 4 + i;
        if (node < N) {
            float4 o;
            o.x = gelu_f(acc[i][0]); o.y = gelu_f(acc[i][1]);
            o.z = gelu_f(acc[i][2]); o.w = gelu_f(acc[i][3]);
            *(float4*)&h1[(long)node * 128 + cg * 4] = o;
        }
    }
}

// ---------------------------------------------------------------------------
// layer2 (folded): {hs,hd} = [h1 | agg2/deg] @ Wc + bc    in=256, out=64
// block 256, 64 nodes/block, 4x4 tile.  Wc 64KB + in 65KB (padded) in LDS.
#define NPB2 64
#define IN2P 260   // 256 + 4 pad: breaks 4-way bank conflict on node-varying reads
__global__ __launch_bounds__(256) void klayer2(
    const float* __restrict__ h1, const float* __restrict__ agg2,
    const float* __restrict__ deg, const float* __restrict__ Wc,
    const float* __restrict__ bc, float* __restrict__ hs, float* __restrict__ hd,
    int N) {
    __shared__ float Wl[256 * 64];       // [k][c2]
    __shared__ float inl[NPB2 * IN2P];   // [n][k] padded
    int t = threadIdx.x;
    for (int idx = t; idx < 256 * 64; idx += 256) Wl[idx] = Wc[idx];
    int base = blockIdx.x * NPB2;
    for (int idx = t; idx < NPB2 * 256; idx += 256) {
        int n = idx >> 8, k = idx & 255;
        int node = base + n;
        float v = 0.f;
        if (node < N) {
            if (k < 128) v = h1[(long)node * 128 + k];
            else         v = agg2[(long)node * 128 + (k - 128)] / fmaxf(deg[node], 1.0f);
        }
        inl[n * IN2P + k] = v;
    }
    __syncthreads();

    int cg = t & 15, ng = t >> 4;        // 16 col-groups x 16 node-groups(4 nodes)
    float4 bv = *(const float4*)(bc + cg * 4);
    float acc[4][4];
#pragma unroll
    for (int i = 0; i < 4; ++i) { acc[i][0]=bv.x; acc[i][1]=bv.y; acc[i][2]=bv.z; acc[i][3]=bv.w; }

#pragma unroll 2
    for (int k4 = 0; k4 < 64; ++k4) {
        float4 w0 = *(const float4*)&Wl[(k4*4+0)*64 + cg*4];
        float4 w1 = *(const float4*)&Wl[(k4*4+1)*64 + cg*4];
        float4 w2 = *(const float4*)&Wl[(k4*4+2)*64 + cg*4];
        float4 w3 = *(const float4*)&Wl[(k4*4+3)*64 + cg*4];
#pragma unroll
        for (int i = 0; i < 4; ++i) {
            float4 iv = *(const float4*)&inl[(ng*4+i)*IN2P + k4*4];
            acc[i][0] += iv.x*w0.x + iv.y*w1.x + iv.z*w2.x + iv.w*w3.x;
            acc[i][1] += iv.x*w0.y + iv.y*w1.y + iv.z*w2.y + iv.w*w3.y;
            acc[i][2] += iv.x*w0.z + iv.y*w1.z + iv.z*w2.z + iv.w*w3.z;
            acc[i][3] += iv.x*w0.w + iv.y*w1.w + iv.z*w2.w + iv.w*w3.w;
        }
    }
#pragma unroll
    for (int i = 0; i < 4; ++i) {
        int node = base + ng * 4 + i;
        if (node < N) {
            float4 o; o.x = acc[i][0]; o.y = acc[i][1]; o.z = acc[i][2]; o.w = acc[i][3];
            if (cg < 8) *(float4*)&hs[(long)node * 32 + cg * 4] = o;
            else        *(float4*)&hd[(long)node * 32 + (cg - 8) * 4] = o;
        }
    }
}

// ---------------------------------------------------------------------------
// edge conv + masked segment_max: only edges with flagged dst (~1% of E)
__global__ void kedgemax(const int* __restrict__ ei, const float* __restrict__ et,
                         const int* __restrict__ flag,
                         const float* __restrict__ hs, const float* __restrict__ hd,
                         const float* __restrict__ wt, const float* __restrict__ bt,
                         unsigned* __restrict__ outm, int E) {
    int e = blockIdx.x * blockDim.x + threadIdx.x;
    if (e >= E) return;
    int d = ei[E + e];
    if (!flag[d]) return;
    int s = ei[e];
    float tm = et[e];
    const float4* hs4 = (const float4*)(hs + (long)s * 32);
    const float4* hd4 = (const float4*)(hd + (long)d * 32);
    const float4* wt4 = (const float4*)wt;
    const float4* bt4 = (const float4*)bt;
    unsigned* om = outm + (long)d * 32;
#pragma unroll
    for (int c4 = 0; c4 < 8; ++c4) {
        float4 a = hs4[c4], b = hd4[c4], w = wt4[c4], bb = bt4[c4];
        float v0 = gelu_f(a.x + b.x + tm * w.x + bb.x);
        float v1 = gelu_f(a.y + b.y + tm * w.y + bb.y);
        float v2 = gelu_f(a.z + b.z + tm * w.z + bb.z);
        float v3 = gelu_f(a.w + b.w + tm * w.w + bb.w);
        atomicMax(om + c4 * 4 + 0, enc_f32(v0));
        atomicMax(om + c4 * 4 + 1, enc_f32(v1));
        atomicMax(om + c4 * 4 + 2, enc_f32(v2));
        atomicMax(om + c4 * 4 + 3, enc_f32(v3));
    }
}

__global__ void kout(const int* __restrict__ mask, const unsigned* __restrict__ outm,
                     float* __restrict__ out, int M) {
    int idx = blockIdx.x * blockDim.x + threadIdx.x;
    if (idx >= M * 32) return;
    int i = idx >> 5, c = idx & 31;
    float f = dec_f32(outm[(long)mask[i] * 32 + c]);
    out[idx] = isfinite(f) ? f : 0.0f;
}

// ---------------------------------------------------------------------------
extern "C" void kernel_launch(void* const* d_in, const int* in_sizes, int n_in,
                              void* d_out, int out_size, void* d_ws, size_t ws_size,
                              hipStream_t stream) {
    const float* x   = (const float*)d_in[0];
    const int*   ei  = (const int*)d_in[1];
    const float* et  = (const float*)d_in[2];
    const int*   mask= (const int*)d_in[3];
    const float* W1r = (const float*)d_in[4];
    const float* W1n = (const float*)d_in[5];
    const float* b1  = (const float*)d_in[6];
    const float* W2r = (const float*)d_in[7];
    const float* W2n = (const float*)d_in[8];
    const float* b2  = (const float*)d_in[9];
    const float* Wts = (const float*)d_in[10];
    const float* Wtd = (const float*)d_in[11];
    const float* wt  = (const float*)d_in[12];
    const float* bt  = (const float*)d_in[13];

    int N = in_sizes[0] / 64;
    int E = in_sizes[1] / 2;
    int M = in_sizes[3];

    float* ws = (float*)d_ws;
    size_t off = 0;
    float*    deg  = ws + off; off += (size_t)N;
    float*    agg1 = ws + off; off += (size_t)N * 64;
    float*    agg2 = ws + off; off += (size_t)N * 128;
    int*      flag = (int*)(ws + off); off += (size_t)N;
    unsigned* outm = (unsigned*)(ws + off); off += (size_t)N * 32;
    size_t zero_words = off;            // deg..outm contiguous, zero in one pass
    float*    h1   = ws + off; off += (size_t)N * 128;
    float*    hs   = ws + off; off += (size_t)N * 32;
    float*    hd   = ws + off; off += (size_t)N * 32;
    float*    Wc   = ws + off; off += 256 * 64;
    float*    bc   = ws + off; off += 64;

    kzero<<<2048, 256, 0, stream>>>((float4*)ws, (long)(zero_words / 4));
    kflag<<<(M + 255) / 256, 256, 0, stream>>>(mask, M, flag);
    kwc<<<65, 256, 0, stream>>>(W2r, W2n, b2, Wts, Wtd, Wc, bc);

    long t1 = (long)E * 16;
    kscatter1<<<(int)((t1 + 255) / 256), 256, 0, stream>>>(ei, x, agg1, deg, E);
    klayer1<<<(N + NPB1 - 1) / NPB1, 256, 0, stream>>>(x, agg1, deg, W1r, W1n, b1, h1, N);

    long t2 = (long)E * 32;
    kscatter2<<<(int)((t2 + 255) / 256), 256, 0, stream>>>(ei, h1, agg2, E);
    klayer2<<<(N + NPB2 - 1) / NPB2, 256, 0, stream>>>(h1, agg2, deg, Wc, bc, hs, hd, N);

    kedgemax<<<(E + 255) / 256, 256, 0, stream>>>(ei, et, flag, hs, hd, wt, bt, outm, E);
    kout<<<(M * 32 + 255) / 256, 256, 0, stream>>>(mask, outm, (float*)d_out, M);
}

// Round 2
// 767.152 us; speedup vs baseline: 5.7837x; 5.7837x over previous
//
#include <hip/hip_runtime.h>
#include <math.h>

// ---------------------------------------------------------------------------
// GraphEncoder round 2: atomic scatters -> CSR gather.
//  * CSR build per launch: kdeg (int atomics) -> 3-kernel prefix scan -> kfill
//  * kagg1/kagg2: one wave per dst node, lane-per-dim coalesced gather, writes
//    MEAN directly (deg = rowptr diff)
//  * layer2 GEMM stays folded: hs,hd = [h1|mean2] @ (W2cat@Wt) + b2@Wt
//  * segment_max still masked-only via order-preserving u32 atomicMax
// ---------------------------------------------------------------------------

__device__ __forceinline__ float gelu_f(float x) {
    const float c0 = 0.7978845608028654f; // sqrt(2/pi)
    float x3 = x * x * x;
    float t = tanhf(c0 * (x + 0.044715f * x3));
    return 0.5f * x * (1.0f + t);
}

// order-preserving float->u32 (monotone): max on u32 == max on float
__device__ __forceinline__ unsigned enc_f32(float f) {
    unsigned u = __float_as_uint(f);
    return (u & 0x80000000u) ? ~u : (u | 0x80000000u);
}
__device__ __forceinline__ float dec_f32(unsigned u) {
    return (u & 0x80000000u) ? __uint_as_float(u & 0x7fffffffu)
                             : __uint_as_float(~u);
}

// ---------------------------------------------------------------------------
__global__ void kzero(float4* __restrict__ p, long n4) {
    long i = (long)blockIdx.x * blockDim.x + threadIdx.x;
    long stride = (long)gridDim.x * blockDim.x;
    float4 z = make_float4(0.f, 0.f, 0.f, 0.f);
    for (; i < n4; i += stride) p[i] = z;
}

__global__ void kflag(const int* __restrict__ mask, int M, int* __restrict__ flag) {
    int i = blockIdx.x * blockDim.x + threadIdx.x;
    if (i < M) flag[mask[i]] = 1;
}

// folded layer2 weight: Wc[k*64 + c2], c2 = mat*32+j (mat0=Wts path, mat1=Wtd)
__global__ void kwc(const float* __restrict__ W2r, const float* __restrict__ W2n,
                    const float* __restrict__ b2,
                    const float* __restrict__ Wts, const float* __restrict__ Wtd,
                    float* __restrict__ Wc, float* __restrict__ bc) {
    if (blockIdx.x < 64) {
        int idx = blockIdx.x * 256 + threadIdx.x;   // 0..16383
        int k = idx >> 6, c2 = idx & 63;
        int mat = c2 >> 5, j = c2 & 31;
        const float* Wt = mat ? Wtd : Wts;
        const float* W2row = (k < 128) ? (W2r + (long)k * 256)
                                       : (W2n + (long)(k - 128) * 256);
        float acc = 0.f;
        for (int j2 = 0; j2 < 256; ++j2) acc += W2row[j2] * Wt[j2 * 32 + j];
        Wc[idx] = acc;
    } else {
        int t = threadIdx.x;
        if (t < 64) {
            int mat = t >> 5, j = t & 31;
            const float* Wt = mat ? Wtd : Wts;
            float acc = 0.f;
            for (int j2 = 0; j2 < 256; ++j2) acc += b2[j2] * Wt[j2 * 32 + j];
            bc[t] = acc;
        }
    }
}

// ---------------------------------------------------------------------------
// CSR build
__global__ void kdeg(const int* __restrict__ ei, int E, int* __restrict__ deg) {
    int e = blockIdx.x * blockDim.x + threadIdx.x;
    if (e < E) atomicAdd(&deg[ei[E + e]], 1);
}

#define SCAN_CHUNK 1024
__global__ void kblocksum(const int* __restrict__ deg, int N, int* __restrict__ part) {
    __shared__ int sd[256];
    int t = threadIdx.x;
    int base = blockIdx.x * SCAN_CHUNK + t * 4;
    int s = 0;
    if (base + 3 < N) {
        int4 v = *(const int4*)&deg[base];
        s = v.x + v.y + v.z + v.w;
    } else {
        for (int k = 0; k < 4; ++k) if (base + k < N) s += deg[base + k];
    }
    sd[t] = s; __syncthreads();
    for (int o = 128; o > 0; o >>= 1) {
        if (t < o) sd[t] += sd[t + o];
        __syncthreads();
    }
    if (t == 0) part[blockIdx.x] = sd[0];
}

__global__ void kscanpart(int* __restrict__ part, int nblk, int* __restrict__ rowptr, int N) {
    if (threadIdx.x == 0 && blockIdx.x == 0) {
        int run = 0;
        for (int i = 0; i < nblk; ++i) { int v = part[i]; part[i] = run; run += v; }
        rowptr[N] = run;   // == E
    }
}

__global__ void kscanchunk(const int* __restrict__ deg, int N,
                           const int* __restrict__ part, int* __restrict__ rowptr) {
    __shared__ int sums[256];
    int t = threadIdx.x;
    int base = blockIdx.x * SCAN_CHUNK + t * 4;
    int v0 = 0, v1 = 0, v2 = 0, v3 = 0;
    if (base + 3 < N) {
        int4 v = *(const int4*)&deg[base];
        v0 = v.x; v1 = v.y; v2 = v.z; v3 = v.w;
    } else {
        if (base     < N) v0 = deg[base];
        if (base + 1 < N) v1 = deg[base + 1];
        if (base + 2 < N) v2 = deg[base + 2];
        if (base + 3 < N) v3 = deg[base + 3];
    }
    int ts = v0 + v1 + v2 + v3;
    sums[t] = ts; __syncthreads();
    for (int o = 1; o < 256; o <<= 1) {           // Hillis-Steele inclusive
        int val = (t >= o) ? sums[t - o] : 0;
        __syncthreads();
        sums[t] += val;
        __syncthreads();
    }
    int excl = sums[t] - ts + part[blockIdx.x];
    int r0 = excl, r1 = r0 + v0, r2 = r1 + v1, r3 = r2 + v2;
    if (base + 3 < N) {
        *(int4*)&rowptr[base] = make_int4(r0, r1, r2, r3);
    } else {
        if (base     < N) rowptr[base]     = r0;
        if (base + 1 < N) rowptr[base + 1] = r1;
        if (base + 2 < N) rowptr[base + 2] = r2;
        if (base + 3 < N) rowptr[base + 3] = r3;
    }
}

__global__ void kfill(const int* __restrict__ ei, int E, const int* __restrict__ rowptr,
                      int* __restrict__ cur, int* __restrict__ csr) {
    int e = blockIdx.x * blockDim.x + threadIdx.x;
    if (e >= E) return;
    int s = ei[e], d = ei[E + e];
    int pos = atomicAdd(&cur[d], 1);
    csr[rowptr[d] + pos] = s;
}

// ---------------------------------------------------------------------------
// gather-mean 1: mean1[n][0:64] = mean of x[src] over CSR row n.  1 wave/node.
__global__ __launch_bounds__(256) void kagg1(const float* __restrict__ x,
                                             const int* __restrict__ rowptr,
                                             const int* __restrict__ csr,
                                             float* __restrict__ mean1, int N) {
    int wid = (int)(((long)blockIdx.x * blockDim.x + threadIdx.x) >> 6);
    int lane = threadIdx.x & 63;
    if (wid >= N) return;
    int beg = rowptr[wid], end = rowptr[wid + 1];
    float acc = 0.f;
    int j = beg;
    for (; j + 4 <= end; j += 4) {
        int s0 = csr[j], s1 = csr[j + 1], s2 = csr[j + 2], s3 = csr[j + 3];
        float a0 = x[(long)s0 * 64 + lane];
        float a1 = x[(long)s1 * 64 + lane];
        float a2 = x[(long)s2 * 64 + lane];
        float a3 = x[(long)s3 * 64 + lane];
        acc += a0 + a1 + a2 + a3;
    }
    for (; j < end; ++j) acc += x[(long)csr[j] * 64 + lane];
    float inv = 1.f / fmaxf((float)(end - beg), 1.f);
    mean1[(long)wid * 64 + lane] = acc * inv;
}

// gather-mean 2: mean2[n][0:128] = mean of h1[src].  1 wave/node, float2/lane.
__global__ __launch_bounds__(256) void kagg2(const float* __restrict__ h1,
                                             const int* __restrict__ rowptr,
                                             const int* __restrict__ csr,
                                             float* __restrict__ mean2, int N) {
    int wid = (int)(((long)blockIdx.x * blockDim.x + threadIdx.x) >> 6);
    int lane = threadIdx.x & 63;
    if (wid >= N) return;
    int beg = rowptr[wid], end = rowptr[wid + 1];
    float ax = 0.f, ay = 0.f;
    int j = beg;
    for (; j + 4 <= end; j += 4) {
        int s0 = csr[j], s1 = csr[j + 1], s2 = csr[j + 2], s3 = csr[j + 3];
        float2 a0 = *(const float2*)&h1[(long)s0 * 128 + lane * 2];
        float2 a1 = *(const float2*)&h1[(long)s1 * 128 + lane * 2];
        float2 a2 = *(const float2*)&h1[(long)s2 * 128 + lane * 2];
        float2 a3 = *(const float2*)&h1[(long)s3 * 128 + lane * 2];
        ax += a0.x + a1.x + a2.x + a3.x;
        ay += a0.y + a1.y + a2.y + a3.y;
    }
    for (; j < end; ++j) {
        float2 a = *(const float2*)&h1[(long)csr[j] * 128 + lane * 2];
        ax += a.x; ay += a.y;
    }
    float inv = 1.f / fmaxf((float)(end - beg), 1.f);
    float2 o; o.x = ax * inv; o.y = ay * inv;
    *(float2*)&mean2[(long)wid * 128 + lane * 2] = o;
}

// ---------------------------------------------------------------------------
// layer1: h1 = gelu([x | mean1] @ [W1r;W1n] + b1)   in=128, out=128
#define NPB1 32
__global__ __launch_bounds__(256) void klayer1(
    const float* __restrict__ x, const float* __restrict__ mean1,
    const float* __restrict__ W1r, const float* __restrict__ W1n,
    const float* __restrict__ b1, float* __restrict__ h1, int N) {
    __shared__ float Wl[128 * 128];      // [k][col]
    __shared__ float inl[NPB1 * 128];    // [n][k]
    int t = threadIdx.x;
    for (int idx = t; idx < 128 * 128; idx += 256) {
        int k = idx >> 7, c = idx & 127;
        Wl[idx] = (k < 64) ? W1r[k * 128 + c] : W1n[(k - 64) * 128 + c];
    }
    int base = blockIdx.x * NPB1;
    for (int idx = t; idx < NPB1 * 128; idx += 256) {
        int n = idx >> 7, k = idx & 127;
        int node = base + n;
        float v = 0.f;
        if (node < N) {
            if (k < 64) v = x[(long)node * 64 + k];
            else        v = mean1[(long)node * 64 + (k - 64)];
        }
        inl[idx] = v;
    }
    __syncthreads();

    int cg = t & 31, ng = t >> 5;
    float4 bv = *(const float4*)(b1 + cg * 4);
    float acc[4][4];
#pragma unroll
    for (int i = 0; i < 4; ++i) { acc[i][0]=bv.x; acc[i][1]=bv.y; acc[i][2]=bv.z; acc[i][3]=bv.w; }

#pragma unroll 2
    for (int k4 = 0; k4 < 32; ++k4) {
        float4 w0 = *(const float4*)&Wl[(k4*4+0)*128 + cg*4];
        float4 w1 = *(const float4*)&Wl[(k4*4+1)*128 + cg*4];
        float4 w2 = *(const float4*)&Wl[(k4*4+2)*128 + cg*4];
        float4 w3 = *(const float4*)&Wl[(k4*4+3)*128 + cg*4];
#pragma unroll
        for (int i = 0; i < 4; ++i) {
            float4 iv = *(const float4*)&inl[(ng*4+i)*128 + k4*4];
            acc[i][0] += iv.x*w0.x + iv.y*w1.x + iv.z*w2.x + iv.w*w3.x;
            acc[i][1] += iv.x*w0.y + iv.y*w1.y + iv.z*w2.y + iv.w*w3.y;
            acc[i][2] += iv.x*w0.z + iv.y*w1.z + iv.z*w2.z + iv.w*w3.z;
            acc[i][3] += iv.x*w0.w + iv.y*w1.w + iv.z*w2.w + iv.w*w3.w;
        }
    }
#pragma unroll
    for (int i = 0; i < 4; ++i) {
        int node = base + ng * 4 + i;
        if (node < N) {
            float4 o;
            o.x = gelu_f(acc[i][0]); o.y = gelu_f(acc[i][1]);
            o.z = gelu_f(acc[i][2]); o.w = gelu_f(acc[i][3]);
            *(float4*)&h1[(long)node * 128 + cg * 4] = o;
        }
    }
}

// ---------------------------------------------------------------------------
// layer2 (folded): {hs,hd} = [h1 | mean2] @ Wc + bc    in=256, out=64
#define NPB2 64
#define IN2P 260
__global__ __launch_bounds__(256) void klayer2(
    const float* __restrict__ h1, const float* __restrict__ mean2,
    const float* __restrict__ Wc, const float* __restrict__ bc,
    float* __restrict__ hs, float* __restrict__ hd, int N) {
    __shared__ float Wl[256 * 64];       // [k][c2]
    __shared__ float inl[NPB2 * IN2P];   // [n][k] padded
    int t = threadIdx.x;
    for (int idx = t; idx < 256 * 64; idx += 256) Wl[idx] = Wc[idx];
    int base = blockIdx.x * NPB2;
    for (int idx = t; idx < NPB2 * 256; idx += 256) {
        int n = idx >> 8, k = idx & 255;
        int node = base + n;
        float v = 0.f;
        if (node < N) {
            if (k < 128) v = h1[(long)node * 128 + k];
            else         v = mean2[(long)node * 128 + (k - 128)];
        }
        inl[n * IN2P + k] = v;
    }
    __syncthreads();

    int cg = t & 15, ng = t >> 4;
    float4 bv = *(const float4*)(bc + cg * 4);
    float acc[4][4];
#pragma unroll
    for (int i = 0; i < 4; ++i) { acc[i][0]=bv.x; acc[i][1]=bv.y; acc[i][2]=bv.z; acc[i][3]=bv.w; }

#pragma unroll 2
    for (int k4 = 0; k4 < 64; ++k4) {
        float4 w0 = *(const float4*)&Wl[(k4*4+0)*64 + cg*4];
        float4 w1 = *(const float4*)&Wl[(k4*4+1)*64 + cg*4];
        float4 w2 = *(const float4*)&Wl[(k4*4+2)*64 + cg*4];
        float4 w3 = *(const float4*)&Wl[(k4*4+3)*64 + cg*4];
#pragma unroll
        for (int i = 0; i < 4; ++i) {
            float4 iv = *(const float4*)&inl[(ng*4+i)*IN2P + k4*4];
            acc[i][0] += iv.x*w0.x + iv.y*w1.x + iv.z*w2.x + iv.w*w3.x;
            acc[i][1] += iv.x*w0.y + iv.y*w1.y + iv.z*w2.y + iv.w*w3.y;
            acc[i][2] += iv.x*w0.z + iv.y*w1.z + iv.z*w2.z + iv.w*w3.z;
            acc[i][3] += iv.x*w0.w + iv.y*w1.w + iv.z*w2.w + iv.w*w3.w;
        }
    }
#pragma unroll
    for (int i = 0; i < 4; ++i) {
        int node = base + ng * 4 + i;
        if (node < N) {
            float4 o; o.x = acc[i][0]; o.y = acc[i][1]; o.z = acc[i][2]; o.w = acc[i][3];
            if (cg < 8) *(float4*)&hs[(long)node * 32 + cg * 4] = o;
            else        *(float4*)&hd[(long)node * 32 + (cg - 8) * 4] = o;
        }
    }
}

// ---------------------------------------------------------------------------
__global__ void kedgemax(const int* __restrict__ ei, const float* __restrict__ et,
                         const int* __restrict__ flag,
                         const float* __restrict__ hs, const float* __restrict__ hd,
                         const float* __restrict__ wt, const float* __restrict__ bt,
                         unsigned* __restrict__ outm, int E) {
    int e = blockIdx.x * blockDim.x + threadIdx.x;
    if (e >= E) return;
    int d = ei[E + e];
    if (!flag[d]) return;
    int s = ei[e];
    float tm = et[e];
    const float4* hs4 = (const float4*)(hs + (long)s * 32);
    const float4* hd4 = (const float4*)(hd + (long)d * 32);
    const float4* wt4 = (const float4*)wt;
    const float4* bt4 = (const float4*)bt;
    unsigned* om = outm + (long)d * 32;
#pragma unroll
    for (int c4 = 0; c4 < 8; ++c4) {
        float4 a = hs4[c4], b = hd4[c4], w = wt4[c4], bb = bt4[c4];
        float v0 = gelu_f(a.x + b.x + tm * w.x + bb.x);
        float v1 = gelu_f(a.y + b.y + tm * w.y + bb.y);
        float v2 = gelu_f(a.z + b.z + tm * w.z + bb.z);
        float v3 = gelu_f(a.w + b.w + tm * w.w + bb.w);
        atomicMax(om + c4 * 4 + 0, enc_f32(v0));
        atomicMax(om + c4 * 4 + 1, enc_f32(v1));
        atomicMax(om + c4 * 4 + 2, enc_f32(v2));
        atomicMax(om + c4 * 4 + 3, enc_f32(v3));
    }
}

__global__ void kout(const int* __restrict__ mask, const unsigned* __restrict__ outm,
                     float* __restrict__ out, int M) {
    int idx = blockIdx.x * blockDim.x + threadIdx.x;
    if (idx >= M * 32) return;
    int i = idx >> 5, c = idx & 31;
    float f = dec_f32(outm[(long)mask[i] * 32 + c]);
    out[idx] = isfinite(f) ? f : 0.0f;
}

// ---------------------------------------------------------------------------
extern "C" void kernel_launch(void* const* d_in, const int* in_sizes, int n_in,
                              void* d_out, int out_size, void* d_ws, size_t ws_size,
                              hipStream_t stream) {
    const float* x   = (const float*)d_in[0];
    const int*   ei  = (const int*)d_in[1];
    const float* et  = (const float*)d_in[2];
    const int*   mask= (const int*)d_in[3];
    const float* W1r = (const float*)d_in[4];
    const float* W1n = (const float*)d_in[5];
    const float* b1  = (const float*)d_in[6];
    const float* W2r = (const float*)d_in[7];
    const float* W2n = (const float*)d_in[8];
    const float* b2  = (const float*)d_in[9];
    const float* Wts = (const float*)d_in[10];
    const float* Wtd = (const float*)d_in[11];
    const float* wt  = (const float*)d_in[12];
    const float* bt  = (const float*)d_in[13];

    int N = in_sizes[0] / 64;
    int E = in_sizes[1] / 2;
    int M = in_sizes[3];

    float* ws = (float*)d_ws;
    size_t off = 0;
    auto pad4 = [](size_t w) { return (w + 3) & ~(size_t)3; };
    int*      deg    = (int*)(ws + off);      off += pad4(N);
    int*      cur    = (int*)(ws + off);      off += pad4(N);
    int*      flag   = (int*)(ws + off);      off += pad4(N);
    unsigned* outm   = (unsigned*)(ws + off); off += pad4((size_t)N * 32);
    size_t zero_words = off;                  // deg..outm zeroed in one pass
    int*      rowptr = (int*)(ws + off);      off += pad4(N + 1);
    int*      csr    = (int*)(ws + off);      off += pad4(E);
    float*    aggbuf = ws + off;              off += pad4((size_t)N * 128); // mean1 / mean2
    float*    h1     = ws + off;              off += pad4((size_t)N * 128);
    float*    hs     = ws + off;              off += pad4((size_t)N * 32);
    float*    hd     = ws + off;              off += pad4((size_t)N * 32);
    float*    Wc     = ws + off;              off += 256 * 64;
    float*    bc     = ws + off;              off += 64;
    int*      part   = (int*)(ws + off);      off += 128;

    int nblk = (N + SCAN_CHUNK - 1) / SCAN_CHUNK;

    kzero<<<2048, 256, 0, stream>>>((float4*)ws, (long)(zero_words / 4));
    kflag<<<(M + 255) / 256, 256, 0, stream>>>(mask, M, flag);
    kwc<<<65, 256, 0, stream>>>(W2r, W2n, b2, Wts, Wtd, Wc, bc);

    // CSR build
    kdeg<<<(E + 255) / 256, 256, 0, stream>>>(ei, E, deg);
    kblocksum<<<nblk, 256, 0, stream>>>(deg, N, part);
    kscanpart<<<1, 64, 0, stream>>>(part, nblk, rowptr, N);
    kscanchunk<<<nblk, 256, 0, stream>>>(deg, N, part, rowptr);
    kfill<<<(E + 255) / 256, 256, 0, stream>>>(ei, E, rowptr, cur, csr);

    // layer 1
    kagg1<<<(N + 3) / 4, 256, 0, stream>>>(x, rowptr, csr, aggbuf, N);
    klayer1<<<(N + NPB1 - 1) / NPB1, 256, 0, stream>>>(x, aggbuf, W1r, W1n, b1, h1, N);

    // layer 2 (folded)
    kagg2<<<(N + 3) / 4, 256, 0, stream>>>(h1, rowptr, csr, aggbuf, N);
    klayer2<<<(N + NPB2 - 1) / NPB2, 256, 0, stream>>>(h1, aggbuf, Wc, bc, hs, hd, N);

    // temporal edge conv + masked segment_max
    kedgemax<<<(E + 255) / 256, 256, 0, stream>>>(ei, et, flag, hs, hd, wt, bt, outm, E);
    kout<<<(M * 32 + 255) / 256, 256, 0, stream>>>(mask, outm, (float*)d_out, M);
}

// Round 3
// 520.675 us; speedup vs baseline: 8.5216x; 1.4734x over previous
//
#include <hip/hip_runtime.h>
#include <math.h>

// ---------------------------------------------------------------------------
// GraphEncoder round 3: bf16 MFMA layers (no LDS), 64-dim layer-2 aggregation,
// masked-edge compaction.
//   h1  = gelu([x|mean1]_bf16 @ W1t_pk + b1)           (MFMA, 16x16x32)
//   [hsd|z] = h1 @ [Wc1|Wc2]_pk  (+bc on hsd)          (MFMA)
//   final = hsd + mean_over_neighbors(z)               (64-dim gather)
//   out = segment_max over masked-dst edges only
// Weights pre-packed into MFMA fragment order at prep time (lane-contiguous).
// A-frags load direct from global (8 contiguous bf16 along K per lane).
// k-order inside a fragment cancels between A and B; C/D layout is the
// m89-verified col=lane&15, row=(lane>>4)*4+reg.
// ---------------------------------------------------------------------------

typedef __attribute__((ext_vector_type(8))) short short8;   // 8 bf16 = 4 VGPR
typedef __attribute__((ext_vector_type(4))) float f32x4;

__device__ __forceinline__ float gelu_f(float x) {
    const float c0 = 0.7978845608028654f; // sqrt(2/pi)
    float x3 = x * x * x;
    float t = tanhf(c0 * (x + 0.044715f * x3));
    return 0.5f * x * (1.0f + t);
}
__device__ __forceinline__ unsigned short f2b(float f) {   // f32 -> bf16 RNE
    unsigned u = __float_as_uint(f);
    u += 0x7fffu + ((u >> 16) & 1);
    return (unsigned short)(u >> 16);
}
__device__ __forceinline__ float b2f(unsigned short h) {
    return __uint_as_float(((unsigned)h) << 16);
}
__device__ __forceinline__ unsigned enc_f32(float f) {     // order-preserving
    unsigned u = __float_as_uint(f);
    return (u & 0x80000000u) ? ~u : (u | 0x80000000u);
}
__device__ __forceinline__ float dec_f32(unsigned u) {
    return (u & 0x80000000u) ? __uint_as_float(u & 0x7fffffffu)
                             : __uint_as_float(~u);
}
// fragment-order position for packed weights: element (outcol c, k)
__device__ __forceinline__ int bpkpos(int c, int k) {
    int s = k >> 5, g = (k >> 3) & 3, e = k & 7, cg = c >> 4, lm = c & 15;
    return ((s * 8 + cg) * 64 + g * 16 + lm) * 8 + e;
}

// ---------------------------------------------------------------------------
// init: zero the atomic/output region + convert x -> bf16 into A1 cols 0..63
__global__ void kinit(float4* __restrict__ z4, long n4, const float* __restrict__ x,
                      unsigned short* __restrict__ A1, int N) {
    long i = (long)blockIdx.x * blockDim.x + threadIdx.x;
    if (i < n4) { z4[i] = make_float4(0.f, 0.f, 0.f, 0.f); return; }
    long j = i - n4;
    if (j >= (long)N * 16) return;
    int node = (int)(j >> 4), c4 = (int)(j & 15);
    float4 v = *(const float4*)(x + (long)node * 64 + c4 * 4);
    ushort4 o;
    o.x = f2b(v.x); o.y = f2b(v.y); o.z = f2b(v.z); o.w = f2b(v.w);
    *(ushort4*)(A1 + (long)node * 128 + c4 * 4) = o;
}

__global__ void kflag(const int* __restrict__ mask, int M, int* __restrict__ flag) {
    int i = blockIdx.x * blockDim.x + threadIdx.x;
    if (i < M) flag[mask[i]] = 1;
}

// pack W1 (transposed) -> B1pk ; fold W2@Wt -> B2pk ; b2@Wt -> bc
__global__ void kprep(const float* __restrict__ W1r, const float* __restrict__ W1n,
                      const float* __restrict__ W2r, const float* __restrict__ W2n,
                      const float* __restrict__ b2,
                      const float* __restrict__ Wts, const float* __restrict__ Wtd,
                      unsigned short* __restrict__ B1pk, unsigned short* __restrict__ B2pk,
                      float* __restrict__ bc) {
    int b = blockIdx.x, t = threadIdx.x;
    if (b < 64) {                       // B1: outcol c (0..127), k (0..127)
        int idx = b * 256 + t;
        int c = idx >> 7, k = idx & 127;
        float v = (k < 64) ? W1r[k * 128 + c] : W1n[(k - 64) * 128 + c];
        B1pk[bpkpos(c, k)] = f2b(v);
    } else if (b < 128) {               // B2: c<64 direct (W2r path), c>=64 neigh (W2n)
        int idx = (b - 64) * 256 + t;
        int c = idx >> 7, k = idx & 127;
        const float* Wrow = (c >= 64) ? (W2n + (long)k * 256) : (W2r + (long)k * 256);
        const float* Wt = ((c >> 5) & 1) ? Wtd : Wts;
        int j32 = c & 31;
        float acc = 0.f;
        for (int j = 0; j < 256; ++j) acc += Wrow[j] * Wt[j * 32 + j32];
        B2pk[bpkpos(c, k)] = f2b(acc);
    } else {
        if (t < 64) {
            const float* Wt = ((t >> 5) & 1) ? Wtd : Wts;
            int j32 = t & 31;
            float a = 0.f;
            for (int j = 0; j < 256; ++j) a += b2[j] * Wt[j * 32 + j32];
            bc[t] = a;
        }
    }
}

// ---------------------------------------------------------------------------
// CSR build
__global__ void kdeg(const int* __restrict__ ei, int E, int* __restrict__ deg) {
    int e = blockIdx.x * blockDim.x + threadIdx.x;
    if (e < E) atomicAdd(&deg[ei[E + e]], 1);
}

#define SCAN_CHUNK 1024
__global__ void kblocksum(const int* __restrict__ deg, int N, int* __restrict__ part) {
    __shared__ int sd[256];
    int t = threadIdx.x;
    int base = blockIdx.x * SCAN_CHUNK + t * 4;
    int s = 0;
    if (base + 3 < N) {
        int4 v = *(const int4*)&deg[base];
        s = v.x + v.y + v.z + v.w;
    } else {
        for (int k = 0; k < 4; ++k) if (base + k < N) s += deg[base + k];
    }
    sd[t] = s; __syncthreads();
    for (int o = 128; o > 0; o >>= 1) {
        if (t < o) sd[t] += sd[t + o];
        __syncthreads();
    }
    if (t == 0) part[blockIdx.x] = sd[0];
}

__global__ void kscanpart(int* __restrict__ part, int nblk, int* __restrict__ rowptr, int N) {
    if (threadIdx.x == 0 && blockIdx.x == 0) {
        int run = 0;
        for (int i = 0; i < nblk; ++i) { int v = part[i]; part[i] = run; run += v; }
        rowptr[N] = run;
    }
}

__global__ void kscanchunk(const int* __restrict__ deg, int N,
                           const int* __restrict__ part, int* __restrict__ rowptr) {
    __shared__ int sums[256];
    int t = threadIdx.x;
    int base = blockIdx.x * SCAN_CHUNK + t * 4;
    int v0 = 0, v1 = 0, v2 = 0, v3 = 0;
    if (base + 3 < N) {
        int4 v = *(const int4*)&deg[base];
        v0 = v.x; v1 = v.y; v2 = v.z; v3 = v.w;
    } else {
        if (base     < N) v0 = deg[base];
        if (base + 1 < N) v1 = deg[base + 1];
        if (base + 2 < N) v2 = deg[base + 2];
        if (base + 3 < N) v3 = deg[base + 3];
    }
    int ts = v0 + v1 + v2 + v3;
    sums[t] = ts; __syncthreads();
    for (int o = 1; o < 256; o <<= 1) {
        int val = (t >= o) ? sums[t - o] : 0;
        __syncthreads();
        sums[t] += val;
        __syncthreads();
    }
    int excl = sums[t] - ts + part[blockIdx.x];
    int r0 = excl, r1 = r0 + v0, r2 = r1 + v1, r3 = r2 + v2;
    if (base + 3 < N) {
        *(int4*)&rowptr[base] = make_int4(r0, r1, r2, r3);
    } else {
        if (base     < N) rowptr[base]     = r0;
        if (base + 1 < N) rowptr[base + 1] = r1;
        if (base + 2 < N) rowptr[base + 2] = r2;
        if (base + 3 < N) rowptr[base + 3] = r3;
    }
}

// fill CSR + compact masked-dst edges
__global__ void kfill(const int* __restrict__ ei, int E, const int* __restrict__ rowptr,
                      int* __restrict__ cur, int* __restrict__ csr,
                      const int* __restrict__ flag, int* __restrict__ nme,
                      int* __restrict__ medge) {
    int e = blockIdx.x * blockDim.x + threadIdx.x;
    if (e >= E) return;
    int s = ei[e], d = ei[E + e];
    int pos = atomicAdd(&cur[d], 1);
    csr[rowptr[d] + pos] = s;
    if (flag[d]) {
        int p = atomicAdd(nme, 1);
        medge[p] = e;
    }
}

// ---------------------------------------------------------------------------
// mean over neighbors of x_bf16 (A1 cols 0..63) -> A1 cols 64..127. 1 wave/node.
__global__ __launch_bounds__(256) void kagg1(unsigned short* __restrict__ A1,
                                             const int* __restrict__ rowptr,
                                             const int* __restrict__ csr, int N) {
    int wid = (blockIdx.x << 2) + (threadIdx.x >> 6);
    int lane = threadIdx.x & 63;
    if (wid >= N) return;
    int beg = rowptr[wid], end = rowptr[wid + 1];
    float acc = 0.f;
    int j = beg;
    for (; j + 4 <= end; j += 4) {
        int s0 = csr[j], s1 = csr[j + 1], s2 = csr[j + 2], s3 = csr[j + 3];
        acc += b2f(A1[(long)s0 * 128 + lane]) + b2f(A1[(long)s1 * 128 + lane])
             + b2f(A1[(long)s2 * 128 + lane]) + b2f(A1[(long)s3 * 128 + lane]);
    }
    for (; j < end; ++j) acc += b2f(A1[(long)csr[j] * 128 + lane]);
    float inv = 1.f / fmaxf((float)(end - beg), 1.f);
    A1[(long)wid * 128 + 64 + lane] = f2b(acc * inv);
}

// ---------------------------------------------------------------------------
// GEMM1: h1 = gelu(A1 @ W1 + b1), M=N nodes, K=128, Ncols=128. 32 rows/wave.
__global__ __launch_bounds__(256) void kgemm1(const unsigned short* __restrict__ A1,
                                              const unsigned short* __restrict__ B1pk,
                                              const float* __restrict__ b1,
                                              unsigned short* __restrict__ h1, int N) {
    int l = threadIdx.x & 63, wv = threadIdx.x >> 6;
    int lm = l & 15, lh = l >> 4;
    long base = (long)blockIdx.x * 128 + wv * 32;
    int r0 = (int)base + lm;      if (r0 > N - 1) r0 = N - 1;
    int r1 = (int)base + 16 + lm; if (r1 > N - 1) r1 = N - 1;
    const unsigned short* a0p = A1 + (long)r0 * 128 + lh * 8;
    const unsigned short* a1p = A1 + (long)r1 * 128 + lh * 8;
    const short8* bp = (const short8*)B1pk;
    f32x4 acc[2][8];
#pragma unroll
    for (int rg = 0; rg < 2; ++rg)
#pragma unroll
        for (int cg = 0; cg < 8; ++cg) acc[rg][cg] = (f32x4){0.f, 0.f, 0.f, 0.f};
#pragma unroll
    for (int s = 0; s < 4; ++s) {
        short8 a0 = *(const short8*)(a0p + s * 32);
        short8 a1 = *(const short8*)(a1p + s * 32);
#pragma unroll
        for (int cg = 0; cg < 8; ++cg) {
            short8 b = bp[(s * 8 + cg) * 64 + l];
            acc[0][cg] = __builtin_amdgcn_mfma_f32_16x16x32_bf16(a0, b, acc[0][cg], 0, 0, 0);
            acc[1][cg] = __builtin_amdgcn_mfma_f32_16x16x32_bf16(a1, b, acc[1][cg], 0, 0, 0);
        }
    }
#pragma unroll
    for (int cg = 0; cg < 8; ++cg) {
        float bv = b1[cg * 16 + lm];
#pragma unroll
        for (int rg = 0; rg < 2; ++rg) {
#pragma unroll
            for (int r = 0; r < 4; ++r) {
                long row = base + rg * 16 + lh * 4 + r;
                if (row < N)
                    h1[row * 128 + cg * 16 + lm] = f2b(gelu_f(acc[rg][cg][r] + bv));
            }
        }
    }
}

// GEMM2: cols 0..63 -> hsd (f32, +bc) ; cols 64..127 -> z (bf16)
__global__ __launch_bounds__(256) void kgemm2(const unsigned short* __restrict__ h1,
                                              const unsigned short* __restrict__ B2pk,
                                              const float* __restrict__ bc,
                                              float* __restrict__ hsd,
                                              unsigned short* __restrict__ z, int N) {
    int l = threadIdx.x & 63, wv = threadIdx.x >> 6;
    int lm = l & 15, lh = l >> 4;
    long base = (long)blockIdx.x * 128 + wv * 32;
    int r0 = (int)base + lm;      if (r0 > N - 1) r0 = N - 1;
    int r1 = (int)base + 16 + lm; if (r1 > N - 1) r1 = N - 1;
    const unsigned short* a0p = h1 + (long)r0 * 128 + lh * 8;
    const unsigned short* a1p = h1 + (long)r1 * 128 + lh * 8;
    const short8* bp = (const short8*)B2pk;
    f32x4 acc[2][8];
#pragma unroll
    for (int rg = 0; rg < 2; ++rg)
#pragma unroll
        for (int cg = 0; cg < 8; ++cg) acc[rg][cg] = (f32x4){0.f, 0.f, 0.f, 0.f};
#pragma unroll
    for (int s = 0; s < 4; ++s) {
        short8 a0 = *(const short8*)(a0p + s * 32);
        short8 a1 = *(const short8*)(a1p + s * 32);
#pragma unroll
        for (int cg = 0; cg < 8; ++cg) {
            short8 b = bp[(s * 8 + cg) * 64 + l];
            acc[0][cg] = __builtin_amdgcn_mfma_f32_16x16x32_bf16(a0, b, acc[0][cg], 0, 0, 0);
            acc[1][cg] = __builtin_amdgcn_mfma_f32_16x16x32_bf16(a1, b, acc[1][cg], 0, 0, 0);
        }
    }
#pragma unroll
    for (int cg = 0; cg < 4; ++cg) {          // direct part
        float bv = bc[cg * 16 + lm];
#pragma unroll
        for (int rg = 0; rg < 2; ++rg)
#pragma unroll
            for (int r = 0; r < 4; ++r) {
                long row = base + rg * 16 + lh * 4 + r;
                if (row < N) hsd[row * 64 + cg * 16 + lm] = acc[rg][cg][r] + bv;
            }
    }
#pragma unroll
    for (int cg = 4; cg < 8; ++cg) {          // neighbor part -> z
#pragma unroll
        for (int rg = 0; rg < 2; ++rg)
#pragma unroll
            for (int r = 0; r < 4; ++r) {
                long row = base + rg * 16 + lh * 4 + r;
                if (row < N) z[row * 64 + (cg - 4) * 16 + lm] = f2b(acc[rg][cg][r]);
            }
    }
}

// ---------------------------------------------------------------------------
// final = hsd + mean over neighbors of z.  1 wave/node, lane = dim (64).
__global__ __launch_bounds__(256) void kagg3(const unsigned short* __restrict__ z,
                                             const float* __restrict__ hsd,
                                             const int* __restrict__ rowptr,
                                             const int* __restrict__ csr,
                                             float* __restrict__ finalv, int N) {
    int wid = (blockIdx.x << 2) + (threadIdx.x >> 6);
    int lane = threadIdx.x & 63;
    if (wid >= N) return;
    int beg = rowptr[wid], end = rowptr[wid + 1];
    float acc = 0.f;
    int j = beg;
    for (; j + 4 <= end; j += 4) {
        int s0 = csr[j], s1 = csr[j + 1], s2 = csr[j + 2], s3 = csr[j + 3];
        acc += b2f(z[(long)s0 * 64 + lane]) + b2f(z[(long)s1 * 64 + lane])
             + b2f(z[(long)s2 * 64 + lane]) + b2f(z[(long)s3 * 64 + lane]);
    }
    for (; j < end; ++j) acc += b2f(z[(long)csr[j] * 64 + lane]);
    float inv = 1.f / fmaxf((float)(end - beg), 1.f);
    finalv[(long)wid * 64 + lane] = hsd[(long)wid * 64 + lane] + acc * inv;
}

// ---------------------------------------------------------------------------
// edge conv + segment_max over the compacted masked-edge list only
__global__ void kedgemax(const int* __restrict__ nme, const int* __restrict__ medge,
                         const int* __restrict__ ei, const float* __restrict__ et,
                         const float* __restrict__ finalv,
                         const float* __restrict__ wt, const float* __restrict__ bt,
                         unsigned* __restrict__ outm, int E) {
    int nm = *nme;
    for (int i = blockIdx.x * blockDim.x + threadIdx.x; i < nm;
         i += gridDim.x * blockDim.x) {
        int e = medge[i];
        int s = ei[e], d = ei[E + e];
        float tm = et[e];
        const float4* a4 = (const float4*)(finalv + (long)s * 64);       // hs
        const float4* b4 = (const float4*)(finalv + (long)d * 64 + 32);  // hd
        const float4* wt4 = (const float4*)wt;
        const float4* bt4 = (const float4*)bt;
        unsigned* om = outm + (long)d * 32;
#pragma unroll
        for (int c4 = 0; c4 < 8; ++c4) {
            float4 a = a4[c4], b = b4[c4], w = wt4[c4], bb = bt4[c4];
            float v0 = gelu_f(a.x + b.x + tm * w.x + bb.x);
            float v1 = gelu_f(a.y + b.y + tm * w.y + bb.y);
            float v2 = gelu_f(a.z + b.z + tm * w.z + bb.z);
            float v3 = gelu_f(a.w + b.w + tm * w.w + bb.w);
            atomicMax(om + c4 * 4 + 0, enc_f32(v0));
            atomicMax(om + c4 * 4 + 1, enc_f32(v1));
            atomicMax(om + c4 * 4 + 2, enc_f32(v2));
            atomicMax(om + c4 * 4 + 3, enc_f32(v3));
        }
    }
}

__global__ void kout(const int* __restrict__ mask, const unsigned* __restrict__ outm,
                     float* __restrict__ out, int M) {
    int idx = blockIdx.x * blockDim.x + threadIdx.x;
    if (idx >= M * 32) return;
    int i = idx >> 5, c = idx & 31;
    float f = dec_f32(outm[(long)mask[i] * 32 + c]);
    out[idx] = isfinite(f) ? f : 0.0f;
}

// ---------------------------------------------------------------------------
extern "C" void kernel_launch(void* const* d_in, const int* in_sizes, int n_in,
                              void* d_out, int out_size, void* d_ws, size_t ws_size,
                              hipStream_t stream) {
    const float* x   = (const float*)d_in[0];
    const int*   ei  = (const int*)d_in[1];
    const float* et  = (const float*)d_in[2];
    const int*   mask= (const int*)d_in[3];
    const float* W1r = (const float*)d_in[4];
    const float* W1n = (const float*)d_in[5];
    const float* b1  = (const float*)d_in[6];
    const float* W2r = (const float*)d_in[7];
    const float* W2n = (const float*)d_in[8];
    const float* b2  = (const float*)d_in[9];
    const float* Wts = (const float*)d_in[10];
    const float* Wtd = (const float*)d_in[11];
    const float* wt  = (const float*)d_in[12];
    const float* bt  = (const float*)d_in[13];

    int N = in_sizes[0] / 64;
    int E = in_sizes[1] / 2;
    int M = in_sizes[3];

    float* ws = (float*)d_ws;
    size_t off = 0;
    auto pad4 = [](size_t w) { return (w + 3) & ~(size_t)3; };
    // --- zeroed region (contiguous from ws[0]) ---
    int*      deg    = (int*)(ws + off);      off += pad4(N);
    int*      cur    = (int*)(ws + off);      off += pad4(N);
    int*      flag   = (int*)(ws + off);      off += pad4(N);
    int*      nme    = (int*)(ws + off);      off += 4;
    unsigned* outm   = (unsigned*)(ws + off); off += pad4((size_t)N * 32);
    size_t zero_words = off;
    // --- rest ---
    int*      rowptr = (int*)(ws + off);      off += pad4(N + 1);
    int*      csr    = (int*)(ws + off);      off += pad4(E);
    int*      medge  = (int*)(ws + off);      off += pad4(E);
    int*      part   = (int*)(ws + off);      off += 128;
    float*    bc     = ws + off;              off += 64;
    unsigned short* B1pk = (unsigned short*)(ws + off); off += 8192;  // 16384 bf16
    unsigned short* B2pk = (unsigned short*)(ws + off); off += 8192;
    unsigned short* A1   = (unsigned short*)(ws + off); off += pad4((size_t)N * 64);
    unsigned short* h1   = (unsigned short*)(ws + off); off += pad4((size_t)N * 64);
    float*    hsd    = ws + off;              off += pad4((size_t)N * 64);
    unsigned short* zb   = (unsigned short*)(ws + off); off += pad4((size_t)N * 32);
    float*    finalv = ws + off;              off += pad4((size_t)N * 64);

    int nblk = (N + SCAN_CHUNK - 1) / SCAN_CHUNK;
    long n4z = (long)(zero_words / 4);
    long init_total = n4z + (long)N * 16;

    kinit<<<(int)((init_total + 255) / 256), 256, 0, stream>>>(
        (float4*)ws, n4z, x, A1, N);
    kflag<<<(M + 255) / 256, 256, 0, stream>>>(mask, M, flag);
    kprep<<<129, 256, 0, stream>>>(W1r, W1n, W2r, W2n, b2, Wts, Wtd, B1pk, B2pk, bc);

    // CSR build
    kdeg<<<(E + 255) / 256, 256, 0, stream>>>(ei, E, deg);
    kblocksum<<<nblk, 256, 0, stream>>>(deg, N, part);
    kscanpart<<<1, 64, 0, stream>>>(part, nblk, rowptr, N);
    kscanchunk<<<nblk, 256, 0, stream>>>(deg, N, part, rowptr);
    kfill<<<(E + 255) / 256, 256, 0, stream>>>(ei, E, rowptr, cur, csr, flag, nme, medge);

    // layer 1
    kagg1<<<(N + 3) / 4, 256, 0, stream>>>(A1, rowptr, csr, N);
    kgemm1<<<(N + 127) / 128, 256, 0, stream>>>(A1, B1pk, b1, h1, N);

    // layer 2 (folded, aggregate in 64-dim)
    kgemm2<<<(N + 127) / 128, 256, 0, stream>>>(h1, B2pk, bc, hsd, zb, N);
    kagg3<<<(N + 3) / 4, 256, 0, stream>>>(zb, hsd, rowptr, csr, finalv, N);

    // temporal edge conv + masked segment_max
    kedgemax<<<128, 256, 0, stream>>>(nme, medge, ei, et, finalv, wt, bt, outm, E);
    kout<<<(M * 32 + 255) / 256, 256, 0, stream>>>(mask, outm, (float*)d_out, M);
}

// Round 4
// 455.719 us; speedup vs baseline: 9.7362x; 1.1425x over previous
//
#include <hip/hip_runtime.h>
#include <math.h>

// ---------------------------------------------------------------------------
// GraphEncoder round 4: bucketed counting-sort CSR build (kills kfill's
// 108MB scattered-write amplification), masked-only outm zeroing, fused
// prep/flag/hist kernel.  Pipeline:
//   kinit   : zero flag/counters + x -> bf16 (A1 cols 0..63)
//   kmisc   : [prep: pack W1, fold W2@Wt] | [flag + zero masked outm rows]
//             | [bucket histogram of dst>>9]
//   kscanb  : bucket prefix -> bstart/gcur, rowptr[N]=E
//   kbin    : bucket scatter of (dlow|src), contiguous per-block runs;
//             masked-edge compaction
//   kcsr    : per-bucket 512-bin counting sort -> rowptr + csr
//   kagg1   : mean(x[src]) -> A1 cols 64..127
//   kgemm1  : h1 = gelu(A1 @ W1pk + b1)            (MFMA 16x16x32 bf16)
//   kgemm2  : [hsd|z] = h1 @ B2pk (+bc on hsd)     (MFMA)
//   kagg3   : final = hsd + mean(z[src])
//   kedgemax: gelu edge conv + atomicMax, masked edges only
//   kout    : decode
// ---------------------------------------------------------------------------

typedef __attribute__((ext_vector_type(8))) short short8;   // 8 bf16 = 4 VGPR
typedef __attribute__((ext_vector_type(4))) float f32x4;

#define NB 256          // bucket count (dst>>9), 196 used for N=100000
#define CBK 32          // edges per thread in kbin
#define MEDGE_CAP 262144

__device__ __forceinline__ float gelu_f(float x) {
    const float c0 = 0.7978845608028654f; // sqrt(2/pi)
    float x3 = x * x * x;
    float t = tanhf(c0 * (x + 0.044715f * x3));
    return 0.5f * x * (1.0f + t);
}
__device__ __forceinline__ unsigned short f2b(float f) {   // f32 -> bf16 RNE
    unsigned u = __float_as_uint(f);
    u += 0x7fffu + ((u >> 16) & 1);
    return (unsigned short)(u >> 16);
}
__device__ __forceinline__ float b2f(unsigned short h) {
    return __uint_as_float(((unsigned)h) << 16);
}
__device__ __forceinline__ unsigned enc_f32(float f) {     // order-preserving
    unsigned u = __float_as_uint(f);
    return (u & 0x80000000u) ? ~u : (u | 0x80000000u);
}
__device__ __forceinline__ float dec_f32(unsigned u) {
    return (u & 0x80000000u) ? __uint_as_float(u & 0x7fffffffu)
                             : __uint_as_float(~u);
}
// fragment-order position for packed weights: element (outcol c, k)
__device__ __forceinline__ int bpkpos(int c, int k) {
    int s = k >> 5, g = (k >> 3) & 3, e = k & 7, cg = c >> 4, lm = c & 15;
    return ((s * 8 + cg) * 64 + g * 16 + lm) * 8 + e;
}

// ---------------------------------------------------------------------------
// zero small region + convert x -> bf16 into A1 cols 0..63
__global__ void kinit(float4* __restrict__ z4, long n4, const float* __restrict__ x,
                      unsigned short* __restrict__ A1, int N) {
    long i = (long)blockIdx.x * blockDim.x + threadIdx.x;
    if (i < n4) { z4[i] = make_float4(0.f, 0.f, 0.f, 0.f); return; }
    long j = i - n4;
    if (j >= (long)N * 16) return;
    int node = (int)(j >> 4), c4 = (int)(j & 15);
    float4 v = *(const float4*)(x + (long)node * 64 + c4 * 4);
    ushort4 o;
    o.x = f2b(v.x); o.y = f2b(v.y); o.z = f2b(v.z); o.w = f2b(v.w);
    *(ushort4*)(A1 + (long)node * 128 + c4 * 4) = o;
}

// ---------------------------------------------------------------------------
// fused: weight prep | flag + masked outm-row zero | bucket histogram
__global__ __launch_bounds__(256) void kmisc(
    const float* __restrict__ W1r, const float* __restrict__ W1n,
    const float* __restrict__ W2r, const float* __restrict__ W2n,
    const float* __restrict__ b2,
    const float* __restrict__ Wts, const float* __restrict__ Wtd,
    const int* __restrict__ ei, int E, const int* __restrict__ mask, int M, int fb,
    unsigned short* __restrict__ B1pk, unsigned short* __restrict__ B2pk,
    float* __restrict__ bc, int* __restrict__ flag, unsigned* __restrict__ outm,
    int* __restrict__ bcnt) {
    __shared__ int h[NB];
    int b = blockIdx.x, t = threadIdx.x;
    if (b < 64) {                        // B1 pack: outcol c (0..127), k (0..127)
        int idx = b * 256 + t;
        int c = idx >> 7, k = idx & 127;
        float v = (k < 64) ? W1r[k * 128 + c] : W1n[(k - 64) * 128 + c];
        B1pk[bpkpos(c, k)] = f2b(v);
    } else if (b < 128) {                // B2 fold: c<64 direct(W2r), c>=64 neigh(W2n)
        int idx = (b - 64) * 256 + t;
        int c = idx >> 7, k = idx & 127;
        const float* Wrow = (c >= 64) ? (W2n + (long)k * 256) : (W2r + (long)k * 256);
        const float* Wt = ((c >> 5) & 1) ? Wtd : Wts;
        int j32 = c & 31;
        float acc = 0.f;
        for (int j = 0; j < 256; ++j) acc += Wrow[j] * Wt[j * 32 + j32];
        B2pk[bpkpos(c, k)] = f2b(acc);
    } else if (b == 128) {               // bc fold
        if (t < 64) {
            const float* Wt = ((t >> 5) & 1) ? Wtd : Wts;
            int j32 = t & 31;
            float a = 0.f;
            for (int j = 0; j < 256; ++j) a += b2[j] * Wt[j * 32 + j32];
            bc[t] = a;
        }
    } else if (b < 129 + fb) {           // flag + zero masked outm rows
        int i = (b - 129) * 256 + t;
        if (i < M) {
            int node = mask[i];
            flag[node] = 1;
            unsigned* om = outm + (long)node * 32;
#pragma unroll
            for (int c = 0; c < 32; ++c) om[c] = 0u;
        }
    } else {                             // bucket histogram, 4096 edges/block
        h[t] = 0;
        __syncthreads();
        long base = (long)(b - 129 - fb) * 4096;
#pragma unroll
        for (int j = 0; j < 16; ++j) {
            long e = base + j * 256 + t;
            if (e < E) atomicAdd(&h[ei[E + e] >> 9], 1);
        }
        __syncthreads();
        if (h[t]) atomicAdd(&bcnt[t], h[t]);
    }
}

// bucket exclusive prefix (256 entries, 1 block serial)
__global__ void kscanb(const int* __restrict__ bcnt, int* __restrict__ bstart,
                       int* __restrict__ gcur, int* __restrict__ rowptr, int N, int E) {
    if (threadIdx.x == 0 && blockIdx.x == 0) {
        int run = 0;
        for (int i = 0; i < NB; ++i) {
            bstart[i] = run; gcur[i] = run; run += bcnt[i];
        }
        rowptr[N] = run;   // == E
    }
}

// bucket scatter: contiguous per-(block,bucket) runs + masked-edge compaction
__global__ __launch_bounds__(256) void kbin(const int* __restrict__ ei, int E,
        const int* __restrict__ flag, int* __restrict__ gcur,
        unsigned* __restrict__ bkt, int* __restrict__ nme, int* __restrict__ medge) {
    __shared__ int hist[NB];
    __shared__ int base[NB];
    long cb = (long)blockIdx.x * (256 * CBK);
    int t = threadIdx.x;
    hist[t] = 0;
    __syncthreads();
    int lpos[CBK];
#pragma unroll
    for (int j = 0; j < CBK; ++j) {
        long e = cb + (long)j * 256 + t;
        if (e < E) lpos[j] = atomicAdd(&hist[ei[E + e] >> 9], 1);
    }
    __syncthreads();
    { int hc = hist[t]; base[t] = hc ? atomicAdd(&gcur[t], hc) : 0; }
    __syncthreads();
#pragma unroll
    for (int j = 0; j < CBK; ++j) {
        long e = cb + (long)j * 256 + t;
        if (e < E) {
            int s = ei[e], d = ei[E + e];
            int bu = d >> 9;
            bkt[base[bu] + lpos[j]] = ((unsigned)(d & 511) << 17) | (unsigned)s;
            if (flag[d]) {
                int p = atomicAdd(nme, 1);
                if (p < MEDGE_CAP) medge[p] = (int)e;
            }
        }
    }
}

// per-bucket counting sort: rowptr + csr (single-writer contiguous region)
__global__ __launch_bounds__(256) void kcsr(const unsigned* __restrict__ bkt,
        const int* __restrict__ bstart, const int* __restrict__ bcnt,
        int* __restrict__ rowptr, int* __restrict__ csr, int N) {
    __shared__ int hist[512];
    __shared__ int pref[512];
    int b = blockIdx.x, t = threadIdx.x;
    int s0 = bstart[b], cnt = bcnt[b];
    hist[t] = 0; hist[t + 256] = 0;
    __syncthreads();
    for (int i = t; i < cnt; i += 256)
        atomicAdd(&hist[bkt[s0 + i] >> 17], 1);
    __syncthreads();
    pref[t] = hist[t]; pref[t + 256] = hist[t + 256];
    __syncthreads();
    for (int o = 1; o < 512; o <<= 1) {               // inclusive scan, 512 wide
        int a0 = (t >= o) ? pref[t - o] : 0;
        int a1 = (t + 256 >= o) ? pref[t + 256 - o] : 0;
        __syncthreads();
        pref[t] += a0; pref[t + 256] += a1;
        __syncthreads();
    }
    int e0 = pref[t] - hist[t], e1 = pref[t + 256] - hist[t + 256];  // exclusive
    int nodebase = b << 9;
    if (nodebase + t < N)       rowptr[nodebase + t] = s0 + e0;
    if (nodebase + t + 256 < N) rowptr[nodebase + t + 256] = s0 + e1;
    __syncthreads();
    pref[t] = e0; pref[t + 256] = e1;                 // -> cursors
    __syncthreads();
    for (int i = t; i < cnt; i += 256) {
        unsigned v = bkt[s0 + i];
        int p = atomicAdd(&pref[v >> 17], 1);
        csr[s0 + p] = (int)(v & 0x1FFFFu);
    }
}

// ---------------------------------------------------------------------------
// mean over neighbors of x_bf16 (A1 cols 0..63) -> A1 cols 64..127. 1 wave/node.
__global__ __launch_bounds__(256) void kagg1(unsigned short* __restrict__ A1,
                                             const int* __restrict__ rowptr,
                                             const int* __restrict__ csr, int N) {
    int wid = (blockIdx.x << 2) + (threadIdx.x >> 6);
    int lane = threadIdx.x & 63;
    if (wid >= N) return;
    int beg = rowptr[wid], end = rowptr[wid + 1];
    float acc = 0.f;
    int j = beg;
    for (; j + 4 <= end; j += 4) {
        int s0 = csr[j], s1 = csr[j + 1], s2 = csr[j + 2], s3 = csr[j + 3];
        acc += b2f(A1[(long)s0 * 128 + lane]) + b2f(A1[(long)s1 * 128 + lane])
             + b2f(A1[(long)s2 * 128 + lane]) + b2f(A1[(long)s3 * 128 + lane]);
    }
    for (; j < end; ++j) acc += b2f(A1[(long)csr[j] * 128 + lane]);
    float inv = 1.f / fmaxf((float)(end - beg), 1.f);
    A1[(long)wid * 128 + 64 + lane] = f2b(acc * inv);
}

// ---------------------------------------------------------------------------
// GEMM1: h1 = gelu(A1 @ W1 + b1), K=128, cols=128. 32 rows/wave, no LDS.
__global__ __launch_bounds__(256) void kgemm1(const unsigned short* __restrict__ A1,
                                              const unsigned short* __restrict__ B1pk,
                                              const float* __restrict__ b1,
                                              unsigned short* __restrict__ h1, int N) {
    int l = threadIdx.x & 63, wv = threadIdx.x >> 6;
    int lm = l & 15, lh = l >> 4;
    long base = (long)blockIdx.x * 128 + wv * 32;
    int r0 = (int)base + lm;      if (r0 > N - 1) r0 = N - 1;
    int r1 = (int)base + 16 + lm; if (r1 > N - 1) r1 = N - 1;
    const unsigned short* a0p = A1 + (long)r0 * 128 + lh * 8;
    const unsigned short* a1p = A1 + (long)r1 * 128 + lh * 8;
    const short8* bp = (const short8*)B1pk;
    f32x4 acc[2][8];
#pragma unroll
    for (int rg = 0; rg < 2; ++rg)
#pragma unroll
        for (int cg = 0; cg < 8; ++cg) acc[rg][cg] = (f32x4){0.f, 0.f, 0.f, 0.f};
#pragma unroll
    for (int s = 0; s < 4; ++s) {
        short8 a0 = *(const short8*)(a0p + s * 32);
        short8 a1 = *(const short8*)(a1p + s * 32);
#pragma unroll
        for (int cg = 0; cg < 8; ++cg) {
            short8 b = bp[(s * 8 + cg) * 64 + l];
            acc[0][cg] = __builtin_amdgcn_mfma_f32_16x16x32_bf16(a0, b, acc[0][cg], 0, 0, 0);
            acc[1][cg] = __builtin_amdgcn_mfma_f32_16x16x32_bf16(a1, b, acc[1][cg], 0, 0, 0);
        }
    }
#pragma unroll
    for (int cg = 0; cg < 8; ++cg) {
        float bv = b1[cg * 16 + lm];
#pragma unroll
        for (int rg = 0; rg < 2; ++rg) {
#pragma unroll
            for (int r = 0; r < 4; ++r) {
                long row = base + rg * 16 + lh * 4 + r;
                if (row < N)
                    h1[row * 128 + cg * 16 + lm] = f2b(gelu_f(acc[rg][cg][r] + bv));
            }
        }
    }
}

// GEMM2: cols 0..63 -> hsd (f32, +bc) ; cols 64..127 -> z (bf16)
__global__ __launch_bounds__(256) void kgemm2(const unsigned short* __restrict__ h1,
                                              const unsigned short* __restrict__ B2pk,
                                              const float* __restrict__ bc,
                                              float* __restrict__ hsd,
                                              unsigned short* __restrict__ z, int N) {
    int l = threadIdx.x & 63, wv = threadIdx.x >> 6;
    int lm = l & 15, lh = l >> 4;
    long base = (long)blockIdx.x * 128 + wv * 32;
    int r0 = (int)base + lm;      if (r0 > N - 1) r0 = N - 1;
    int r1 = (int)base + 16 + lm; if (r1 > N - 1) r1 = N - 1;
    const unsigned short* a0p = h1 + (long)r0 * 128 + lh * 8;
    const unsigned short* a1p = h1 + (long)r1 * 128 + lh * 8;
    const short8* bp = (const short8*)B2pk;
    f32x4 acc[2][8];
#pragma unroll
    for (int rg = 0; rg < 2; ++rg)
#pragma unroll
        for (int cg = 0; cg < 8; ++cg) acc[rg][cg] = (f32x4){0.f, 0.f, 0.f, 0.f};
#pragma unroll
    for (int s = 0; s < 4; ++s) {
        short8 a0 = *(const short8*)(a0p + s * 32);
        short8 a1 = *(const short8*)(a1p + s * 32);
#pragma unroll
        for (int cg = 0; cg < 8; ++cg) {
            short8 b = bp[(s * 8 + cg) * 64 + l];
            acc[0][cg] = __builtin_amdgcn_mfma_f32_16x16x32_bf16(a0, b, acc[0][cg], 0, 0, 0);
            acc[1][cg] = __builtin_amdgcn_mfma_f32_16x16x32_bf16(a1, b, acc[1][cg], 0, 0, 0);
        }
    }
#pragma unroll
    for (int cg = 0; cg < 4; ++cg) {          // direct part
        float bv = bc[cg * 16 + lm];
#pragma unroll
        for (int rg = 0; rg < 2; ++rg)
#pragma unroll
            for (int r = 0; r < 4; ++r) {
                long row = base + rg * 16 + lh * 4 + r;
                if (row < N) hsd[row * 64 + cg * 16 + lm] = acc[rg][cg][r] + bv;
            }
    }
#pragma unroll
    for (int cg = 4; cg < 8; ++cg) {          // neighbor part -> z (bf16)
#pragma unroll
        for (int rg = 0; rg < 2; ++rg)
#pragma unroll
            for (int r = 0; r < 4; ++r) {
                long row = base + rg * 16 + lh * 4 + r;
                if (row < N) z[row * 64 + (cg - 4) * 16 + lm] = f2b(acc[rg][cg][r]);
            }
    }
}

// ---------------------------------------------------------------------------
// final = hsd + mean over neighbors of z.  1 wave/node.
__global__ __launch_bounds__(256) void kagg3(const unsigned short* __restrict__ z,
                                             const float* __restrict__ hsd,
                                             const int* __restrict__ rowptr,
                                             const int* __restrict__ csr,
                                             float* __restrict__ finalv, int N) {
    int wid = (blockIdx.x << 2) + (threadIdx.x >> 6);
    int lane = threadIdx.x & 63;
    if (wid >= N) return;
    int beg = rowptr[wid], end = rowptr[wid + 1];
    float acc = 0.f;
    int j = beg;
    for (; j + 4 <= end; j += 4) {
        int s0 = csr[j], s1 = csr[j + 1], s2 = csr[j + 2], s3 = csr[j + 3];
        acc += b2f(z[(long)s0 * 64 + lane]) + b2f(z[(long)s1 * 64 + lane])
             + b2f(z[(long)s2 * 64 + lane]) + b2f(z[(long)s3 * 64 + lane]);
    }
    for (; j < end; ++j) acc += b2f(z[(long)csr[j] * 64 + lane]);
    float inv = 1.f / fmaxf((float)(end - beg), 1.f);
    finalv[(long)wid * 64 + lane] = hsd[(long)wid * 64 + lane] + acc * inv;
}

// ---------------------------------------------------------------------------
__global__ void kedgemax(const int* __restrict__ nme, const int* __restrict__ medge,
                         const int* __restrict__ ei, const float* __restrict__ et,
                         const float* __restrict__ finalv,
                         const float* __restrict__ wt, const float* __restrict__ bt,
                         unsigned* __restrict__ outm, int E) {
    int nm = *nme; if (nm > MEDGE_CAP) nm = MEDGE_CAP;
    for (int i = blockIdx.x * blockDim.x + threadIdx.x; i < nm;
         i += gridDim.x * blockDim.x) {
        int e = medge[i];
        int s = ei[e], d = ei[E + e];
        float tm = et[e];
        const float4* a4 = (const float4*)(finalv + (long)s * 64);       // hs
        const float4* b4 = (const float4*)(finalv + (long)d * 64 + 32);  // hd
        const float4* wt4 = (const float4*)wt;
        const float4* bt4 = (const float4*)bt;
        unsigned* om = outm + (long)d * 32;
#pragma unroll
        for (int c4 = 0; c4 < 8; ++c4) {
            float4 a = a4[c4], b = b4[c4], w = wt4[c4], bb = bt4[c4];
            float v0 = gelu_f(a.x + b.x + tm * w.x + bb.x);
            float v1 = gelu_f(a.y + b.y + tm * w.y + bb.y);
            float v2 = gelu_f(a.z + b.z + tm * w.z + bb.z);
            float v3 = gelu_f(a.w + b.w + tm * w.w + bb.w);
            atomicMax(om + c4 * 4 + 0, enc_f32(v0));
            atomicMax(om + c4 * 4 + 1, enc_f32(v1));
            atomicMax(om + c4 * 4 + 2, enc_f32(v2));
            atomicMax(om + c4 * 4 + 3, enc_f32(v3));
        }
    }
}

__global__ void kout(const int* __restrict__ mask, const unsigned* __restrict__ outm,
                     float* __restrict__ out, int M) {
    int idx = blockIdx.x * blockDim.x + threadIdx.x;
    if (idx >= M * 32) return;
    int i = idx >> 5, c = idx & 31;
    float f = dec_f32(outm[(long)mask[i] * 32 + c]);
    out[idx] = isfinite(f) ? f : 0.0f;
}

// ---------------------------------------------------------------------------
extern "C" void kernel_launch(void* const* d_in, const int* in_sizes, int n_in,
                              void* d_out, int out_size, void* d_ws, size_t ws_size,
                              hipStream_t stream) {
    const float* x   = (const float*)d_in[0];
    const int*   ei  = (const int*)d_in[1];
    const float* et  = (const float*)d_in[2];
    const int*   mask= (const int*)d_in[3];
    const float* W1r = (const float*)d_in[4];
    const float* W1n = (const float*)d_in[5];
    const float* b1  = (const float*)d_in[6];
    const float* W2r = (const float*)d_in[7];
    const float* W2n = (const float*)d_in[8];
    const float* b2  = (const float*)d_in[9];
    const float* Wts = (const float*)d_in[10];
    const float* Wtd = (const float*)d_in[11];
    const float* wt  = (const float*)d_in[12];
    const float* bt  = (const float*)d_in[13];

    int N = in_sizes[0] / 64;
    int E = in_sizes[1] / 2;
    int M = in_sizes[3];

    float* ws = (float*)d_ws;
    size_t off = 0;
    auto pad4 = [](size_t w) { return (w + 3) & ~(size_t)3; };
    // --- zeroed region (contiguous from ws[0]) ---
    int*      flag   = (int*)(ws + off);      off += pad4(N);
    int*      bcnt   = (int*)(ws + off);      off += NB;
    int*      nme    = (int*)(ws + off);      off += 4;
    size_t zero_words = off;
    // --- rest (not zeroed) ---
    int*      bstart = (int*)(ws + off);      off += NB;
    int*      gcur   = (int*)(ws + off);      off += NB;
    int*      rowptr = (int*)(ws + off);      off += pad4(N + 1);
    int*      csr    = (int*)(ws + off);      off += pad4(E);
    unsigned* bkt    = (unsigned*)(ws + off); off += pad4(E);
    int*      medge  = (int*)(ws + off);      off += MEDGE_CAP;
    float*    bc     = ws + off;              off += 64;
    unsigned short* B1pk = (unsigned short*)(ws + off); off += 8192;
    unsigned short* B2pk = (unsigned short*)(ws + off); off += 8192;
    unsigned short* A1   = (unsigned short*)(ws + off); off += pad4((size_t)N * 64);
    unsigned short* h1   = (unsigned short*)(ws + off); off += pad4((size_t)N * 64);
    float*    hsd    = ws + off;              off += pad4((size_t)N * 64);
    unsigned short* zb   = (unsigned short*)(ws + off); off += pad4((size_t)N * 32);
    float*    finalv = ws + off;              off += pad4((size_t)N * 64);
    unsigned* outm   = (unsigned*)(ws + off); off += pad4((size_t)N * 32); // masked rows only

    long n4z = (long)(zero_words / 4);
    long init_total = n4z + (long)N * 16;
    int fb = (M + 255) / 256;                         // flag blocks in kmisc
    int hb = (int)((E + 4095) / 4096);                // hist blocks in kmisc
    int binb = (int)(((long)E + 256 * CBK - 1) / (256 * CBK));
    int nb_used = (N + 511) >> 9;

    kinit<<<(int)((init_total + 255) / 256), 256, 0, stream>>>(
        (float4*)ws, n4z, x, A1, N);
    kmisc<<<129 + fb + hb, 256, 0, stream>>>(W1r, W1n, W2r, W2n, b2, Wts, Wtd,
        ei, E, mask, M, fb, B1pk, B2pk, bc, flag, outm, bcnt);
    kscanb<<<1, 64, 0, stream>>>(bcnt, bstart, gcur, rowptr, N, E);
    kbin<<<binb, 256, 0, stream>>>(ei, E, flag, gcur, bkt, nme, medge);
    kcsr<<<nb_used, 256, 0, stream>>>(bkt, bstart, bcnt, rowptr, csr, N);

    kagg1<<<(N + 3) / 4, 256, 0, stream>>>(A1, rowptr, csr, N);
    kgemm1<<<(N + 127) / 128, 256, 0, stream>>>(A1, B1pk, b1, h1, N);
    kgemm2<<<(N + 127) / 128, 256, 0, stream>>>(h1, B2pk, bc, hsd, zb, N);
    kagg3<<<(N + 3) / 4, 256, 0, stream>>>(zb, hsd, rowptr, csr, finalv, N);

    kedgemax<<<128, 256, 0, stream>>>(nme, medge, ei, et, finalv, wt, bt, outm, E);
    kout<<<(M * 32 + 255) / 256, 256, 0, stream>>>(mask, outm, (float*)d_out, M);
}

// Round 5
// 420.185 us; speedup vs baseline: 10.5596x; 1.0846x over previous
//
#include <hip/hip_runtime.h>
#include <math.h>

// ---------------------------------------------------------------------------
// GraphEncoder round 5:
//  * kbin CBK 32->8 (782 blocks: fixes 8% occupancy grid starvation)
//  * kagg1/kagg3: thread-per-(node, 8-col chunk), 16B short8 loads, no shfl
//  * kagg3 restricted to masked-edge endpoint nodes (nlist, built in kcsr);
//    kbin marks masked-edge srcs with flag bit1
// Pipeline: kinit, kmisc(prep|flag|hist), kscanb, kbin, kcsr(+nlist),
//           kagg1, kgemm1, kgemm2, kagg3(list), kedgemax, kout
// ---------------------------------------------------------------------------

typedef __attribute__((ext_vector_type(8))) short short8;   // 8 bf16 = 4 VGPR
typedef __attribute__((ext_vector_type(4))) float f32x4;

#define NB 256          // bucket count (dst>>9)
#define CBK 8           // edges per thread in kbin
#define MEDGE_CAP 262144

__device__ __forceinline__ float gelu_f(float x) {
    const float c0 = 0.7978845608028654f; // sqrt(2/pi)
    float x3 = x * x * x;
    float t = tanhf(c0 * (x + 0.044715f * x3));
    return 0.5f * x * (1.0f + t);
}
__device__ __forceinline__ unsigned short f2b(float f) {   // f32 -> bf16 RNE
    unsigned u = __float_as_uint(f);
    u += 0x7fffu + ((u >> 16) & 1);
    return (unsigned short)(u >> 16);
}
__device__ __forceinline__ float b2f(unsigned short h) {
    return __uint_as_float(((unsigned)h) << 16);
}
__device__ __forceinline__ unsigned enc_f32(float f) {     // order-preserving
    unsigned u = __float_as_uint(f);
    return (u & 0x80000000u) ? ~u : (u | 0x80000000u);
}
__device__ __forceinline__ float dec_f32(unsigned u) {
    return (u & 0x80000000u) ? __uint_as_float(u & 0x7fffffffu)
                             : __uint_as_float(~u);
}
// fragment-order position for packed weights: element (outcol c, k)
__device__ __forceinline__ int bpkpos(int c, int k) {
    int s = k >> 5, g = (k >> 3) & 3, e = k & 7, cg = c >> 4, lm = c & 15;
    return ((s * 8 + cg) * 64 + g * 16 + lm) * 8 + e;
}

// ---------------------------------------------------------------------------
// zero small region + convert x -> bf16 into A1 cols 0..63
__global__ void kinit(float4* __restrict__ z4, long n4, const float* __restrict__ x,
                      unsigned short* __restrict__ A1, int N) {
    long i = (long)blockIdx.x * blockDim.x + threadIdx.x;
    if (i < n4) { z4[i] = make_float4(0.f, 0.f, 0.f, 0.f); return; }
    long j = i - n4;
    if (j >= (long)N * 16) return;
    int node = (int)(j >> 4), c4 = (int)(j & 15);
    float4 v = *(const float4*)(x + (long)node * 64 + c4 * 4);
    ushort4 o;
    o.x = f2b(v.x); o.y = f2b(v.y); o.z = f2b(v.z); o.w = f2b(v.w);
    *(ushort4*)(A1 + (long)node * 128 + c4 * 4) = o;
}

// ---------------------------------------------------------------------------
// fused: weight prep | flag + masked outm-row zero | bucket histogram
__global__ __launch_bounds__(256) void kmisc(
    const float* __restrict__ W1r, const float* __restrict__ W1n,
    const float* __restrict__ W2r, const float* __restrict__ W2n,
    const float* __restrict__ b2,
    const float* __restrict__ Wts, const float* __restrict__ Wtd,
    const int* __restrict__ ei, int E, const int* __restrict__ mask, int M, int fb,
    unsigned short* __restrict__ B1pk, unsigned short* __restrict__ B2pk,
    float* __restrict__ bc, int* __restrict__ flag, unsigned* __restrict__ outm,
    int* __restrict__ bcnt) {
    __shared__ int h[NB];
    int b = blockIdx.x, t = threadIdx.x;
    if (b < 64) {                        // B1 pack: outcol c (0..127), k (0..127)
        int idx = b * 256 + t;
        int c = idx >> 7, k = idx & 127;
        float v = (k < 64) ? W1r[k * 128 + c] : W1n[(k - 64) * 128 + c];
        B1pk[bpkpos(c, k)] = f2b(v);
    } else if (b < 128) {                // B2 fold: c<64 direct(W2r), c>=64 neigh(W2n)
        int idx = (b - 64) * 256 + t;
        int c = idx >> 7, k = idx & 127;
        const float* Wrow = (c >= 64) ? (W2n + (long)k * 256) : (W2r + (long)k * 256);
        const float* Wt = ((c >> 5) & 1) ? Wtd : Wts;
        int j32 = c & 31;
        float acc = 0.f;
        for (int j = 0; j < 256; ++j) acc += Wrow[j] * Wt[j * 32 + j32];
        B2pk[bpkpos(c, k)] = f2b(acc);
    } else if (b == 128) {               // bc fold
        if (t < 64) {
            const float* Wt = ((t >> 5) & 1) ? Wtd : Wts;
            int j32 = t & 31;
            float a = 0.f;
            for (int j = 0; j < 256; ++j) a += b2[j] * Wt[j * 32 + j32];
            bc[t] = a;
        }
    } else if (b < 129 + fb) {           // flag bit0 + zero masked outm rows
        int i = (b - 129) * 256 + t;
        if (i < M) {
            int node = mask[i];
            atomicOr(&flag[node], 1);
            unsigned* om = outm + (long)node * 32;
#pragma unroll
            for (int c = 0; c < 32; ++c) om[c] = 0u;
        }
    } else {                             // bucket histogram, 4096 edges/block
        h[t] = 0;
        __syncthreads();
        long base = (long)(b - 129 - fb) * 4096;
#pragma unroll
        for (int j = 0; j < 16; ++j) {
            long e = base + j * 256 + t;
            if (e < E) atomicAdd(&h[ei[E + e] >> 9], 1);
        }
        __syncthreads();
        if (h[t]) atomicAdd(&bcnt[t], h[t]);
    }
}

// bucket exclusive prefix (256 entries, 1 block serial)
__global__ void kscanb(const int* __restrict__ bcnt, int* __restrict__ bstart,
                       int* __restrict__ gcur, int* __restrict__ rowptr, int N, int E) {
    if (threadIdx.x == 0 && blockIdx.x == 0) {
        int run = 0;
        for (int i = 0; i < NB; ++i) {
            bstart[i] = run; gcur[i] = run; run += bcnt[i];
        }
        rowptr[N] = run;   // == E
    }
}

// bucket scatter: contiguous per-(block,bucket) runs + masked-edge compaction
// + flag bit1 on masked-edge srcs
__global__ __launch_bounds__(256) void kbin(const int* __restrict__ ei, int E,
        int* __restrict__ flag, int* __restrict__ gcur,
        unsigned* __restrict__ bkt, int* __restrict__ nme, int* __restrict__ medge) {
    __shared__ int hist[NB];
    __shared__ int base[NB];
    long cb = (long)blockIdx.x * (256 * CBK);
    int t = threadIdx.x;
    hist[t] = 0;
    __syncthreads();
    int lpos[CBK];
#pragma unroll
    for (int j = 0; j < CBK; ++j) {
        long e = cb + (long)j * 256 + t;
        if (e < E) lpos[j] = atomicAdd(&hist[ei[E + e] >> 9], 1);
    }
    __syncthreads();
    { int hc = hist[t]; base[t] = hc ? atomicAdd(&gcur[t], hc) : 0; }
    __syncthreads();
#pragma unroll
    for (int j = 0; j < CBK; ++j) {
        long e = cb + (long)j * 256 + t;
        if (e < E) {
            int s = ei[e], d = ei[E + e];
            int bu = d >> 9;
            bkt[base[bu] + lpos[j]] = ((unsigned)(d & 511) << 17) | (unsigned)s;
            if (flag[d] & 1) {
                int p = atomicAdd(nme, 1);
                if (p < MEDGE_CAP) medge[p] = (int)e;
                atomicOr(&flag[s], 2);       // src needs finalv
            }
        }
    }
}

// per-bucket counting sort -> rowptr + csr ; also compact flagged nodes -> nlist
__global__ __launch_bounds__(256) void kcsr(const unsigned* __restrict__ bkt,
        const int* __restrict__ bstart, const int* __restrict__ bcnt,
        const int* __restrict__ flag,
        int* __restrict__ rowptr, int* __restrict__ csr,
        int* __restrict__ nlist, int* __restrict__ nlcnt, int N) {
    __shared__ int hist[512];
    __shared__ int pref[512];
    __shared__ int slist[512];
    __shared__ int lcnt, lbase;
    int b = blockIdx.x, t = threadIdx.x;
    int s0 = bstart[b], cnt = bcnt[b];
    hist[t] = 0; hist[t + 256] = 0;
    if (t == 0) lcnt = 0;
    __syncthreads();
    for (int i = t; i < cnt; i += 256)
        atomicAdd(&hist[bkt[s0 + i] >> 17], 1);
    __syncthreads();
    pref[t] = hist[t]; pref[t + 256] = hist[t + 256];
    __syncthreads();
    for (int o = 1; o < 512; o <<= 1) {               // inclusive scan, 512 wide
        int a0 = (t >= o) ? pref[t - o] : 0;
        int a1 = (t + 256 >= o) ? pref[t + 256 - o] : 0;
        __syncthreads();
        pref[t] += a0; pref[t + 256] += a1;
        __syncthreads();
    }
    int e0 = pref[t] - hist[t], e1 = pref[t + 256] - hist[t + 256];  // exclusive
    int nodebase = b << 9;
    int n0 = nodebase + t, n1 = nodebase + t + 256;
    if (n0 < N) {
        rowptr[n0] = s0 + e0;
        if (flag[n0]) { int p = atomicAdd(&lcnt, 1); slist[p] = n0; }
    }
    if (n1 < N) {
        rowptr[n1] = s0 + e1;
        if (flag[n1]) { int p = atomicAdd(&lcnt, 1); slist[p] = n1; }
    }
    __syncthreads();
    if (t == 0) lbase = atomicAdd(nlcnt, lcnt);
    pref[t] = e0; pref[t + 256] = e1;                 // -> cursors
    __syncthreads();
    if (t < lcnt) nlist[lbase + t] = slist[t];
    if (t + 256 < lcnt) nlist[lbase + t + 256] = slist[t + 256];
    for (int i = t; i < cnt; i += 256) {
        unsigned v = bkt[s0 + i];
        int p = atomicAdd(&pref[v >> 17], 1);
        csr[s0 + p] = (int)(v & 0x1FFFFu);
    }
}

// ---------------------------------------------------------------------------
// mean(x[src]) -> A1 cols 64..127.  8 threads per node, 16B short8 loads.
__global__ __launch_bounds__(256) void kagg1(unsigned short* __restrict__ A1,
                                             const int* __restrict__ rowptr,
                                             const int* __restrict__ csr, int N) {
    int tid = blockIdx.x * 256 + threadIdx.x;
    int n = tid >> 3, c = tid & 7;
    if (n >= N) return;
    int beg = rowptr[n], end = rowptr[n + 1];
    float acc[8] = {0.f, 0.f, 0.f, 0.f, 0.f, 0.f, 0.f, 0.f};
    int j = beg;
    for (; j + 4 <= end; j += 4) {
        int s0 = csr[j], s1 = csr[j + 1], s2 = csr[j + 2], s3 = csr[j + 3];
        short8 v0 = *(const short8*)(A1 + (long)s0 * 128 + c * 8);
        short8 v1 = *(const short8*)(A1 + (long)s1 * 128 + c * 8);
        short8 v2 = *(const short8*)(A1 + (long)s2 * 128 + c * 8);
        short8 v3 = *(const short8*)(A1 + (long)s3 * 128 + c * 8);
#pragma unroll
        for (int k = 0; k < 8; ++k)
            acc[k] += b2f((unsigned short)v0[k]) + b2f((unsigned short)v1[k])
                    + b2f((unsigned short)v2[k]) + b2f((unsigned short)v3[k]);
    }
    for (; j < end; ++j) {
        short8 v = *(const short8*)(A1 + (long)csr[j] * 128 + c * 8);
#pragma unroll
        for (int k = 0; k < 8; ++k) acc[k] += b2f((unsigned short)v[k]);
    }
    float inv = 1.f / fmaxf((float)(end - beg), 1.f);
    unsigned short o[8];
#pragma unroll
    for (int k = 0; k < 8; ++k) o[k] = f2b(acc[k] * inv);
    *(short8*)(A1 + (long)n * 128 + 64 + c * 8) = *(const short8*)o;
}

// ---------------------------------------------------------------------------
// GEMM1: h1 = gelu(A1 @ W1 + b1), K=128, cols=128. 32 rows/wave, no LDS.
__global__ __launch_bounds__(256) void kgemm1(const unsigned short* __restrict__ A1,
                                              const unsigned short* __restrict__ B1pk,
                                              const float* __restrict__ b1,
                                              unsigned short* __restrict__ h1, int N) {
    int l = threadIdx.x & 63, wv = threadIdx.x >> 6;
    int lm = l & 15, lh = l >> 4;
    long base = (long)blockIdx.x * 128 + wv * 32;
    int r0 = (int)base + lm;      if (r0 > N - 1) r0 = N - 1;
    int r1 = (int)base + 16 + lm; if (r1 > N - 1) r1 = N - 1;
    const unsigned short* a0p = A1 + (long)r0 * 128 + lh * 8;
    const unsigned short* a1p = A1 + (long)r1 * 128 + lh * 8;
    const short8* bp = (const short8*)B1pk;
    f32x4 acc[2][8];
#pragma unroll
    for (int rg = 0; rg < 2; ++rg)
#pragma unroll
        for (int cg = 0; cg < 8; ++cg) acc[rg][cg] = (f32x4){0.f, 0.f, 0.f, 0.f};
#pragma unroll
    for (int s = 0; s < 4; ++s) {
        short8 a0 = *(const short8*)(a0p + s * 32);
        short8 a1 = *(const short8*)(a1p + s * 32);
#pragma unroll
        for (int cg = 0; cg < 8; ++cg) {
            short8 b = bp[(s * 8 + cg) * 64 + l];
            acc[0][cg] = __builtin_amdgcn_mfma_f32_16x16x32_bf16(a0, b, acc[0][cg], 0, 0, 0);
            acc[1][cg] = __builtin_amdgcn_mfma_f32_16x16x32_bf16(a1, b, acc[1][cg], 0, 0, 0);
        }
    }
#pragma unroll
    for (int cg = 0; cg < 8; ++cg) {
        float bv = b1[cg * 16 + lm];
#pragma unroll
        for (int rg = 0; rg < 2; ++rg) {
#pragma unroll
            for (int r = 0; r < 4; ++r) {
                long row = base + rg * 16 + lh * 4 + r;
                if (row < N)
                    h1[row * 128 + cg * 16 + lm] = f2b(gelu_f(acc[rg][cg][r] + bv));
            }
        }
    }
}

// GEMM2: cols 0..63 -> hsd (f32, +bc) ; cols 64..127 -> z (bf16)
__global__ __launch_bounds__(256) void kgemm2(const unsigned short* __restrict__ h1,
                                              const unsigned short* __restrict__ B2pk,
                                              const float* __restrict__ bc,
                                              float* __restrict__ hsd,
                                              unsigned short* __restrict__ z, int N) {
    int l = threadIdx.x & 63, wv = threadIdx.x >> 6;
    int lm = l & 15, lh = l >> 4;
    long base = (long)blockIdx.x * 128 + wv * 32;
    int r0 = (int)base + lm;      if (r0 > N - 1) r0 = N - 1;
    int r1 = (int)base + 16 + lm; if (r1 > N - 1) r1 = N - 1;
    const unsigned short* a0p = h1 + (long)r0 * 128 + lh * 8;
    const unsigned short* a1p = h1 + (long)r1 * 128 + lh * 8;
    const short8* bp = (const short8*)B2pk;
    f32x4 acc[2][8];
#pragma unroll
    for (int rg = 0; rg < 2; ++rg)
#pragma unroll
        for (int cg = 0; cg < 8; ++cg) acc[rg][cg] = (f32x4){0.f, 0.f, 0.f, 0.f};
#pragma unroll
    for (int s = 0; s < 4; ++s) {
        short8 a0 = *(const short8*)(a0p + s * 32);
        short8 a1 = *(const short8*)(a1p + s * 32);
#pragma unroll
        for (int cg = 0; cg < 8; ++cg) {
            short8 b = bp[(s * 8 + cg) * 64 + l];
            acc[0][cg] = __builtin_amdgcn_mfma_f32_16x16x32_bf16(a0, b, acc[0][cg], 0, 0, 0);
            acc[1][cg] = __builtin_amdgcn_mfma_f32_16x16x32_bf16(a1, b, acc[1][cg], 0, 0, 0);
        }
    }
#pragma unroll
    for (int cg = 0; cg < 4; ++cg) {          // direct part
        float bv = bc[cg * 16 + lm];
#pragma unroll
        for (int rg = 0; rg < 2; ++rg)
#pragma unroll
            for (int r = 0; r < 4; ++r) {
                long row = base + rg * 16 + lh * 4 + r;
                if (row < N) hsd[row * 64 + cg * 16 + lm] = acc[rg][cg][r] + bv;
            }
    }
#pragma unroll
    for (int cg = 4; cg < 8; ++cg) {          // neighbor part -> z (bf16)
#pragma unroll
        for (int rg = 0; rg < 2; ++rg)
#pragma unroll
            for (int r = 0; r < 4; ++r) {
                long row = base + rg * 16 + lh * 4 + r;
                if (row < N) z[row * 64 + (cg - 4) * 16 + lm] = f2b(acc[rg][cg][r]);
            }
    }
}

// ---------------------------------------------------------------------------
// finalv = hsd + mean(z[src]) for LISTED nodes only.  8 threads/node.
__global__ __launch_bounds__(256) void kagg3(const unsigned short* __restrict__ z,
                                             const float* __restrict__ hsd,
                                             const int* __restrict__ rowptr,
                                             const int* __restrict__ csr,
                                             const int* __restrict__ nlist,
                                             const int* __restrict__ nlcnt,
                                             float* __restrict__ finalv) {
    int cnt = *nlcnt;
    int slots = (gridDim.x * 256) >> 3;
    int slot = (blockIdx.x * 256 + threadIdx.x) >> 3;
    int c = threadIdx.x & 7;
    for (int li = slot; li < cnt; li += slots) {
        int n = nlist[li];
        int beg = rowptr[n], end = rowptr[n + 1];
        float acc[8] = {0.f, 0.f, 0.f, 0.f, 0.f, 0.f, 0.f, 0.f};
        int j = beg;
        for (; j + 4 <= end; j += 4) {
            int s0 = csr[j], s1 = csr[j + 1], s2 = csr[j + 2], s3 = csr[j + 3];
            short8 v0 = *(const short8*)(z + (long)s0 * 64 + c * 8);
            short8 v1 = *(const short8*)(z + (long)s1 * 64 + c * 8);
            short8 v2 = *(const short8*)(z + (long)s2 * 64 + c * 8);
            short8 v3 = *(const short8*)(z + (long)s3 * 64 + c * 8);
#pragma unroll
            for (int k = 0; k < 8; ++k)
                acc[k] += b2f((unsigned short)v0[k]) + b2f((unsigned short)v1[k])
                        + b2f((unsigned short)v2[k]) + b2f((unsigned short)v3[k]);
        }
        for (; j < end; ++j) {
            short8 v = *(const short8*)(z + (long)csr[j] * 64 + c * 8);
#pragma unroll
            for (int k = 0; k < 8; ++k) acc[k] += b2f((unsigned short)v[k]);
        }
        float inv = 1.f / fmaxf((float)(end - beg), 1.f);
        float4 o0, o1;
        const float4* hp = (const float4*)(hsd + (long)n * 64 + c * 8);
        float4 h0 = hp[0], h1v = hp[1];
        o0.x = h0.x + acc[0] * inv; o0.y = h0.y + acc[1] * inv;
        o0.z = h0.z + acc[2] * inv; o0.w = h0.w + acc[3] * inv;
        o1.x = h1v.x + acc[4] * inv; o1.y = h1v.y + acc[5] * inv;
        o1.z = h1v.z + acc[6] * inv; o1.w = h1v.w + acc[7] * inv;
        float4* op = (float4*)(finalv + (long)n * 64 + c * 8);
        op[0] = o0; op[1] = o1;
    }
}

// ---------------------------------------------------------------------------
__global__ void kedgemax(const int* __restrict__ nme, const int* __restrict__ medge,
                         const int* __restrict__ ei, const float* __restrict__ et,
                         const float* __restrict__ finalv,
                         const float* __restrict__ wt, const float* __restrict__ bt,
                         unsigned* __restrict__ outm, int E) {
    int nm = *nme; if (nm > MEDGE_CAP) nm = MEDGE_CAP;
    for (int i = blockIdx.x * blockDim.x + threadIdx.x; i < nm;
         i += gridDim.x * blockDim.x) {
        int e = medge[i];
        int s = ei[e], d = ei[E + e];
        float tm = et[e];
        const float4* a4 = (const float4*)(finalv + (long)s * 64);       // hs
        const float4* b4 = (const float4*)(finalv + (long)d * 64 + 32);  // hd
        const float4* wt4 = (const float4*)wt;
        const float4* bt4 = (const float4*)bt;
        unsigned* om = outm + (long)d * 32;
#pragma unroll
        for (int c4 = 0; c4 < 8; ++c4) {
            float4 a = a4[c4], b = b4[c4], w = wt4[c4], bb = bt4[c4];
            float v0 = gelu_f(a.x + b.x + tm * w.x + bb.x);
            float v1 = gelu_f(a.y + b.y + tm * w.y + bb.y);
            float v2 = gelu_f(a.z + b.z + tm * w.z + bb.z);
            float v3 = gelu_f(a.w + b.w + tm * w.w + bb.w);
            atomicMax(om + c4 * 4 + 0, enc_f32(v0));
            atomicMax(om + c4 * 4 + 1, enc_f32(v1));
            atomicMax(om + c4 * 4 + 2, enc_f32(v2));
            atomicMax(om + c4 * 4 + 3, enc_f32(v3));
        }
    }
}

__global__ void kout(const int* __restrict__ mask, const unsigned* __restrict__ outm,
                     float* __restrict__ out, int M) {
    int idx = blockIdx.x * blockDim.x + threadIdx.x;
    if (idx >= M * 32) return;
    int i = idx >> 5, c = idx & 31;
    float f = dec_f32(outm[(long)mask[i] * 32 + c]);
    out[idx] = isfinite(f) ? f : 0.0f;
}

// ---------------------------------------------------------------------------
extern "C" void kernel_launch(void* const* d_in, const int* in_sizes, int n_in,
                              void* d_out, int out_size, void* d_ws, size_t ws_size,
                              hipStream_t stream) {
    const float* x   = (const float*)d_in[0];
    const int*   ei  = (const int*)d_in[1];
    const float* et  = (const float*)d_in[2];
    const int*   mask= (const int*)d_in[3];
    const float* W1r = (const float*)d_in[4];
    const float* W1n = (const float*)d_in[5];
    const float* b1  = (const float*)d_in[6];
    const float* W2r = (const float*)d_in[7];
    const float* W2n = (const float*)d_in[8];
    const float* b2  = (const float*)d_in[9];
    const float* Wts = (const float*)d_in[10];
    const float* Wtd = (const float*)d_in[11];
    const float* wt  = (const float*)d_in[12];
    const float* bt  = (const float*)d_in[13];

    int N = in_sizes[0] / 64;
    int E = in_sizes[1] / 2;
    int M = in_sizes[3];

    float* ws = (float*)d_ws;
    size_t off = 0;
    auto pad4 = [](size_t w) { return (w + 3) & ~(size_t)3; };
    // --- zeroed region (contiguous from ws[0]) ---
    int*      flag   = (int*)(ws + off);      off += pad4(N);
    int*      bcnt   = (int*)(ws + off);      off += NB;
    int*      nme    = (int*)(ws + off);      off += 4;
    int*      nlcnt  = (int*)(ws + off);      off += 4;
    size_t zero_words = off;
    // --- rest (not zeroed) ---
    int*      bstart = (int*)(ws + off);      off += NB;
    int*      gcur   = (int*)(ws + off);      off += NB;
    int*      rowptr = (int*)(ws + off);      off += pad4(N + 1);
    int*      csr    = (int*)(ws + off);      off += pad4(E);
    unsigned* bkt    = (unsigned*)(ws + off); off += pad4(E);
    int*      medge  = (int*)(ws + off);      off += MEDGE_CAP;
    int*      nlist  = (int*)(ws + off);      off += pad4(N);
    float*    bc     = ws + off;              off += 64;
    unsigned short* B1pk = (unsigned short*)(ws + off); off += 8192;
    unsigned short* B2pk = (unsigned short*)(ws + off); off += 8192;
    unsigned short* A1   = (unsigned short*)(ws + off); off += pad4((size_t)N * 64);
    unsigned short* h1   = (unsigned short*)(ws + off); off += pad4((size_t)N * 64);
    float*    hsd    = ws + off;              off += pad4((size_t)N * 64);
    unsigned short* zb   = (unsigned short*)(ws + off); off += pad4((size_t)N * 32);
    float*    finalv = ws + off;              off += pad4((size_t)N * 64);
    unsigned* outm   = (unsigned*)(ws + off); off += pad4((size_t)N * 32); // masked rows only

    long n4z = (long)(zero_words / 4);
    long init_total = n4z + (long)N * 16;
    int fb = (M + 255) / 256;                         // flag blocks in kmisc
    int hb = (int)((E + 4095) / 4096);                // hist blocks in kmisc
    int binb = (int)(((long)E + 256 * CBK - 1) / (256 * CBK));
    int nb_used = (N + 511) >> 9;

    kinit<<<(int)((init_total + 255) / 256), 256, 0, stream>>>(
        (float4*)ws, n4z, x, A1, N);
    kmisc<<<129 + fb + hb, 256, 0, stream>>>(W1r, W1n, W2r, W2n, b2, Wts, Wtd,
        ei, E, mask, M, fb, B1pk, B2pk, bc, flag, outm, bcnt);
    kscanb<<<1, 64, 0, stream>>>(bcnt, bstart, gcur, rowptr, N, E);
    kbin<<<binb, 256, 0, stream>>>(ei, E, flag, gcur, bkt, nme, medge);
    kcsr<<<nb_used, 256, 0, stream>>>(bkt, bstart, bcnt, flag, rowptr, csr,
                                      nlist, nlcnt, N);

    kagg1<<<(N * 8 + 255) / 256, 256, 0, stream>>>(A1, rowptr, csr, N);
    kgemm1<<<(N + 127) / 128, 256, 0, stream>>>(A1, B1pk, b1, h1, N);
    kgemm2<<<(N + 127) / 128, 256, 0, stream>>>(h1, B2pk, bc, hsd, zb, N);
    kagg3<<<512, 256, 0, stream>>>(zb, hsd, rowptr, csr, nlist, nlcnt, finalv);

    kedgemax<<<128, 256, 0, stream>>>(nme, medge, ei, et, finalv, wt, bt, outm, E);
    kout<<<(M * 32 + 255) / 256, 256, 0, stream>>>(mask, outm, (float*)d_out, M);
}